// Round 26
// baseline (450.551 us; speedup 1.0000x reference)
//
#include <hip/hip_runtime.h>
#include <hip/hip_bf16.h>
#include <hip/hip_fp16.h>

// ---------------------------------------------------------------------------
// DattaBot block: RMSNorm -> QKV -> RoPE -> causal attn -> O-proj+res ->
//                 RMSNorm -> top2/8 MoE (GELU, H=4096) -> res
// Round 26: r23 base (400.4 best). MoE gemm1/gemm2 restructured to the
// guide's minimum-2-phase schedule: ONE barrier per K-step (was 2), stage
// issued before compute, counted WAIT_VM2 so the next tile's loads span the
// barrier. Static brA/brB register double-buffer for the f32 B prefetch
// (loop unrolled x2). MFMA order unchanged -> bit-identical numerics.
// ---------------------------------------------------------------------------

#define T_TOK 2048
#define DMODEL 1024
#define SEQ 1024
#define NEXP 8
#define HEXP 4096

typedef __attribute__((ext_vector_type(4))) float f32x4;
typedef __attribute__((ext_vector_type(4))) int i32x4;
typedef __attribute__((ext_vector_type(8))) short short8;      // 8 bf16
typedef __attribute__((ext_vector_type(8))) _Float16 half8;
typedef __attribute__((ext_vector_type(4))) _Float16 half4;

#define WAIT_VM2 asm volatile("s_waitcnt vmcnt(2)" ::: "memory")
#define WAIT_VM3 asm volatile("s_waitcnt vmcnt(3)" ::: "memory")
#define WAIT_VM4 asm volatile("s_waitcnt vmcnt(4)" ::: "memory")
#define WAIT_VM6 asm volatile("s_waitcnt vmcnt(6)" ::: "memory")
#define WAIT_VM0 asm volatile("s_waitcnt vmcnt(0)" ::: "memory")
#define WAIT_LGKM0 asm volatile("s_waitcnt lgkmcnt(0)" ::: "memory")
#define BARRIER __builtin_amdgcn_s_barrier()
#define SCHEDFENCE __builtin_amdgcn_sched_barrier(0)

// async global->LDS, 16B per lane. LDS dest is wave-uniform base + lane*16;
// global src is per-lane (gather-capable).
__device__ __forceinline__ void gload16(const void* g, void* l)
{
    __builtin_amdgcn_global_load_lds((const __attribute__((address_space(1))) void*)g,
                                     (__attribute__((address_space(3))) void*)l, 16, 0, 0);
}

// split f32 -> bf16 hi + bf16 lo (round-nearest-even both)
__device__ __forceinline__ void bsplit(float f, unsigned short& hi, unsigned short& lo)
{
    unsigned int u = __float_as_uint(f);
    unsigned int rh = (u + 0x7FFFu + ((u >> 16) & 1u)) >> 16;
    hi = (unsigned short)rh;
    float fl = f - __uint_as_float(rh << 16);
    unsigned int u2 = __float_as_uint(fl);
    lo = (unsigned short)((u2 + 0x7FFFu + ((u2 >> 16) & 1u)) >> 16);
}

// tanh-form GELU (max dev from erf-GELU ~3e-4; cheaper than erff by ~3x)
__device__ __forceinline__ float gelu_fast(float v)
{
    float e = __expf(-1.5957691216f * v * (1.0f + 0.044715f * v * v));
    return v * __builtin_amdgcn_rcpf(1.0f + e);
}

// ---------------- split 4 weight matrices f32 -> bf16 hi/lo -----------------
__global__ __launch_bounds__(256) void split4_kernel(
    const float* __restrict__ s0, const float* __restrict__ s1,
    const float* __restrict__ s2, const float* __restrict__ s3,
    unsigned short* __restrict__ h0, unsigned short* __restrict__ h1,
    unsigned short* __restrict__ h2, unsigned short* __restrict__ h3,
    unsigned short* __restrict__ l0, unsigned short* __restrict__ l1,
    unsigned short* __restrict__ l2, unsigned short* __restrict__ l3, int n4)
{
    int z = blockIdx.y;
    const float* src = (z == 0) ? s0 : (z == 1) ? s1 : (z == 2) ? s2 : s3;
    unsigned short* hi = (z == 0) ? h0 : (z == 1) ? h1 : (z == 2) ? h2 : h3;
    unsigned short* lo = (z == 0) ? l0 : (z == 1) ? l1 : (z == 2) ? l2 : l3;
    int stride = gridDim.x * blockDim.x;
    for (int i = blockIdx.x * blockDim.x + threadIdx.x; i < n4; i += stride) {
        float4 v = ((const float4*)src)[i];
        ushort4 h, l;
        bsplit(v.x, h.x, l.x); bsplit(v.y, h.y, l.y);
        bsplit(v.z, h.z, l.z); bsplit(v.w, h.w, l.w);
        *(ushort4*)(hi + (size_t)i * 4) = h;
        *(ushort4*)(lo + (size_t)i * 4) = l;
    }
}

// ---------------- RMSNorm: f32 out / f16 out / bf16-split out (optional) ----
__global__ __launch_bounds__(256) void rmsnorm_kernel(const float* __restrict__ x,
                                                      const float* __restrict__ w,
                                                      float* __restrict__ of,
                                                      _Float16* __restrict__ oh,
                                                      unsigned short* __restrict__ ohi,
                                                      unsigned short* __restrict__ olo)
{
    int row = blockIdx.x;
    int t = threadIdx.x;
    float4 v = ((const float4*)(x + (size_t)row * DMODEL))[t];
    float ss = v.x * v.x + v.y * v.y + v.z * v.z + v.w * v.w;
#pragma unroll
    for (int off = 32; off > 0; off >>= 1) ss += __shfl_xor(ss, off);
    __shared__ float red[4];
    if ((t & 63) == 0) red[t >> 6] = ss;
    __syncthreads();
    float tot = red[0] + red[1] + red[2] + red[3];
    float sc = rsqrtf(tot * (1.0f / DMODEL) + 1e-6f);
    float4 w4 = ((const float4*)w)[t];
    float4 o;
    o.x = v.x * sc * w4.x; o.y = v.y * sc * w4.y; o.z = v.z * sc * w4.z; o.w = v.w * sc * w4.w;
    if (of) ((float4*)(of + (size_t)row * DMODEL))[t] = o;
    if (oh) {
        half4 h = { (_Float16)o.x, (_Float16)o.y, (_Float16)o.z, (_Float16)o.w };
        *(half4*)(oh + (size_t)row * DMODEL + t * 4) = h;
    }
    if (ohi) {
        ushort4 h, l;
        bsplit(o.x, h.x, l.x); bsplit(o.y, h.y, l.y);
        bsplit(o.z, h.z, l.z); bsplit(o.w, h.w, l.w);
        *(ushort4*)(ohi + (size_t)row * DMODEL + t * 4) = h;
        *(ushort4*)(olo + (size_t)row * DMODEL + t * 4) = l;
    }
}

// ---------------- split-bf16 GEMM: C = A*B^T (+resid), 3-term MFMA ----------
// 128x64 tile, BK=32, 2-buffer pipeline with counted vmcnt (6 loads/stage).
__global__ __launch_bounds__(256) void gemm_split_kernel(
    const unsigned short* __restrict__ aH, const unsigned short* __restrict__ aL,
    const unsigned short* __restrict__ b0H, const unsigned short* __restrict__ b0L,
    const unsigned short* __restrict__ b1H, const unsigned short* __restrict__ b1L,
    const unsigned short* __restrict__ b2H, const unsigned short* __restrict__ b2L,
    float* __restrict__ C0, float* __restrict__ C1, float* __restrict__ C2,
    const float* __restrict__ resid, int K)
{
    const unsigned short* bH = (blockIdx.z == 0) ? b0H : (blockIdx.z == 1 ? b1H : b2H);
    const unsigned short* bL = (blockIdx.z == 0) ? b0L : (blockIdx.z == 1 ? b1L : b2L);
    float* C = (blockIdx.z == 0) ? C0 : (blockIdx.z == 1 ? C1 : C2);
    int m0 = blockIdx.y * 128, n0 = blockIdx.x * 64;
    __shared__ unsigned short AsH[2][128 * 32];
    __shared__ unsigned short AsL[2][128 * 32];
    __shared__ unsigned short BsH[2][64 * 32];
    __shared__ unsigned short BsL[2][64 * 32];
    int t = threadIdx.x, w = t >> 6, l = t & 63;
    int sa = l >> 2, sc = (l & 3) * 8;
    const unsigned short* gAH0 = aH + (size_t)(m0 + w * 32 + sa) * K + sc;
    const unsigned short* gAH1 = aH + (size_t)(m0 + w * 32 + 16 + sa) * K + sc;
    const unsigned short* gAL0 = aL + (size_t)(m0 + w * 32 + sa) * K + sc;
    const unsigned short* gAL1 = aL + (size_t)(m0 + w * 32 + 16 + sa) * K + sc;
    const unsigned short* gBH0 = bH + (size_t)(n0 + w * 16 + sa) * K + sc;
    const unsigned short* gBL0 = bL + (size_t)(n0 + w * 16 + sa) * K + sc;
    const int aoff0 = (w * 32) * 32;
    const int aoff1 = (w * 32 + 16) * 32;
    const int boff0 = (w * 16) * 32;
    int wr = w >> 1, wc = w & 1;
    f32x4 zero = { 0.0f, 0.0f, 0.0f, 0.0f };
    f32x4 acc[4][2];
#pragma unroll
    for (int i = 0; i < 4; i++)
#pragma unroll
        for (int j = 0; j < 2; j++) acc[i][j] = zero;

#define GS_STAGE(B, K0) do { \
    gload16(gAH0 + (K0), &AsH[B][aoff0]); gload16(gAH1 + (K0), &AsH[B][aoff1]); \
    gload16(gAL0 + (K0), &AsL[B][aoff0]); gload16(gAL1 + (K0), &AsL[B][aoff1]); \
    gload16(gBH0 + (K0), &BsH[B][boff0]); gload16(gBL0 + (K0), &BsL[B][boff0]); \
} while (0)

#define GS_COMPUTE(B) do { \
    short8 ah[4], al[4], bh8[2], bl8[2]; \
    _Pragma("unroll") \
    for (int mi = 0; mi < 4; mi++) { \
        int base = (wr * 64 + mi * 16 + (l & 15)) * 32 + (l >> 4) * 8; \
        ah[mi] = *(const short8*)&AsH[B][base]; \
        al[mi] = *(const short8*)&AsL[B][base]; } \
    _Pragma("unroll") \
    for (int ni = 0; ni < 2; ni++) { \
        int base = (wc * 32 + ni * 16 + (l & 15)) * 32 + (l >> 4) * 8; \
        bh8[ni] = *(const short8*)&BsH[B][base]; \
        bl8[ni] = *(const short8*)&BsL[B][base]; } \
    _Pragma("unroll") \
    for (int mi = 0; mi < 4; mi++) \
        _Pragma("unroll") \
        for (int ni = 0; ni < 2; ni++) { \
            acc[mi][ni] = __builtin_amdgcn_mfma_f32_16x16x32_bf16(ah[mi], bh8[ni], acc[mi][ni], 0, 0, 0); \
            acc[mi][ni] = __builtin_amdgcn_mfma_f32_16x16x32_bf16(ah[mi], bl8[ni], acc[mi][ni], 0, 0, 0); \
            acc[mi][ni] = __builtin_amdgcn_mfma_f32_16x16x32_bf16(al[mi], bh8[ni], acc[mi][ni], 0, 0, 0); } \
} while (0)

    const int nt = K >> 5;                 // always even (K = 1024)
    GS_STAGE(0, 0);
    for (int kt = 0; kt < nt; kt += 2) {
        GS_STAGE(1, (kt + 1) << 5);
        WAIT_VM6;
        BARRIER; SCHEDFENCE;
        GS_COMPUTE(0);
        BARRIER;
        if (kt + 2 < nt) {
            GS_STAGE(0, (kt + 2) << 5);
            WAIT_VM6;
        } else {
            WAIT_VM0;
        }
        BARRIER; SCHEDFENCE;
        GS_COMPUTE(1);
        BARRIER;
    }
#undef GS_STAGE
#undef GS_COMPUTE

#pragma unroll
    for (int mi = 0; mi < 4; mi++) {
#pragma unroll
        for (int r = 0; r < 4; r++) {
            int row = m0 + wr * 64 + mi * 16 + (l >> 4) * 4 + r;
#pragma unroll
            for (int ni = 0; ni < 2; ni++) {
                int col = n0 + wc * 32 + ni * 16 + (l & 15);
                float v = acc[mi][ni][r];
                if (resid) v += resid[(size_t)row * DMODEL + col];
                C[(size_t)row * DMODEL + col] = v;
            }
        }
    }
}

// ---------------- fused RoPE + split --------------------------------------
// Q out: head-major linear [bh][s][64]. K out: 64-row tiles, XOR-swizzled
// (slot' = slot ^ (row&7)) so attn can gload16 linearly + ds_read swizzled.
__global__ __launch_bounds__(256) void rope_split_kernel(
    const float* __restrict__ qf, const float* __restrict__ kf,
    unsigned short* __restrict__ qHi, unsigned short* __restrict__ qLo,
    unsigned short* __restrict__ kHi, unsigned short* __restrict__ kLo)
{
    int i = blockIdx.x * 256 + threadIdx.x;   // 2048*16*32
    int tok = i >> 9;
    int r = i & 511;
    int hh = r >> 5, ii = r & 31;
    int s = tok & (SEQ - 1);
    int b = tok >> 10;
    float invf = powf(10000.0f, -(float)(2 * ii) * (1.0f / 64.0f));
    float ang = (float)s * invf;
    float c = cosf(ang), sn = sinf(ang);
    size_t base = (size_t)tok * DMODEL + hh * 64 + ii;
    float q1 = qf[base], q2 = qf[base + 32];
    float k1 = kf[base], k2 = kf[base + 32];
    float rq1 = (q1 * c - q2 * sn) * 0.125f;
    float rq2 = (q2 * c + q1 * sn) * 0.125f;
    float rk1 = k1 * c - k2 * sn;
    float rk2 = k2 * c + k1 * sn;
    int bh = b * 16 + hh;
    // Q: linear head-major
    size_t qb = ((size_t)bh * SEQ + s) * 64 + ii;
    unsigned short h, lo;
    bsplit(rq1, h, lo); qHi[qb] = h; qLo[qb] = lo;
    bsplit(rq2, h, lo); qHi[qb + 32] = h; qLo[qb + 32] = lo;
    // K: swizzled tiles [bh][s>>6][row=s&63][swz(d)]
    size_t kb = (size_t)bh * (SEQ * 64) + (size_t)(s >> 6) * 4096 + (size_t)(s & 63) * 64;
    int d1 = ii, d2 = ii + 32;
    int p1 = (((d1 >> 3) ^ (s & 7)) << 3) | (d1 & 7);
    int p2 = (((d2 >> 3) ^ (s & 7)) << 3) | (d2 & 7);
    bsplit(rk1, h, lo); kHi[kb + p1] = h; kLo[kb + p1] = lo;
    bsplit(rk2, h, lo); kHi[kb + p2] = h; kLo[kb + p2] = lo;
}

// ---------------- V transpose+split: -> vt[bh][kt][row=d][swz(scol)] --------
__global__ __launch_bounds__(256) void vtrans_kernel(const float* __restrict__ vf,
                                                     unsigned short* __restrict__ vtHi,
                                                     unsigned short* __restrict__ vtLo)
{
    int sb = blockIdx.x, bh = blockIdx.y;
    int b = bh >> 4, h = bh & 15;
    __shared__ unsigned short tH[64][72];
    __shared__ unsigned short tL[64][72];
    int t = threadIdx.x;
#pragma unroll
    for (int i = 0; i < 4; i++) {
        int idx = i * 256 + t, row = idx >> 4, c4 = idx & 15;
        float4 v = *(const float4*)(vf + (size_t)(b * SEQ + sb * 64 + row) * DMODEL + h * 64 + c4 * 4);
        unsigned short hh, ll;
        bsplit(v.x, hh, ll); tH[c4 * 4 + 0][row] = hh; tL[c4 * 4 + 0][row] = ll;
        bsplit(v.y, hh, ll); tH[c4 * 4 + 1][row] = hh; tL[c4 * 4 + 1][row] = ll;
        bsplit(v.z, hh, ll); tH[c4 * 4 + 2][row] = hh; tL[c4 * 4 + 2][row] = ll;
        bsplit(v.w, hh, ll); tH[c4 * 4 + 3][row] = hh; tL[c4 * 4 + 3][row] = ll;
    }
    __syncthreads();
#pragma unroll
    for (int i = 0; i < 4; i++) {
        int idx = i * 256 + t, d = idx >> 4, sc4 = idx & 15;
        ushort4 oh = { tH[d][sc4 * 4 + 0], tH[d][sc4 * 4 + 1], tH[d][sc4 * 4 + 2], tH[d][sc4 * 4 + 3] };
        ushort4 ol = { tL[d][sc4 * 4 + 0], tL[d][sc4 * 4 + 1], tL[d][sc4 * 4 + 2], tL[d][sc4 * 4 + 3] };
        size_t off = (size_t)bh * (64 * SEQ) + (size_t)sb * 4096 + (size_t)d * 64
                   + (((sc4 >> 1) ^ (d & 7)) << 3) + ((sc4 & 1) << 2);
        *(ushort4*)(vtHi + off) = oh;
        *(ushort4*)(vtLo + off) = ol;
    }
}

// ---------------- MFMA flash attention (split-bf16, causal, KV-split x2) ----
// 8 waves, 128 q-rows/block. K/V tiles staged via global_load_lds (counted
// vmcnt pipeline); swizzled frag reads.
__global__ __launch_bounds__(512) void attn_mfma_kernel(
    const unsigned short* __restrict__ qHi, const unsigned short* __restrict__ qLo,
    const unsigned short* __restrict__ kHi, const unsigned short* __restrict__ kLo,
    const unsigned short* __restrict__ vtHi, const unsigned short* __restrict__ vtLo,
    float* __restrict__ Opart, float* __restrict__ mscr, float* __restrict__ lscr)
{
    int qt = 7 - blockIdx.x;               // reversed: biggest blocks first
    int bh = blockIdx.y, ks = blockIdx.z;
    int t = threadIdx.x, w = t >> 6, l = t & 63;
    int lq = l & 15, g = l >> 4, lx = lq & 7;
    __shared__ unsigned short KsH[2][4096];
    __shared__ unsigned short KsL[2][4096];
    __shared__ unsigned short VsH[2][4096];
    __shared__ unsigned short VsL[2][4096];
    __shared__ unsigned short PsH[8][1024];
    __shared__ unsigned short PsL[8][1024];
    const size_t hb = (size_t)bh * (SEQ * 64);
    const unsigned short* kHp = kHi + hb;
    const unsigned short* kLp = kLo + hb;
    const unsigned short* vHp = vtHi + hb;
    const unsigned short* vLp = vtLo + hb;
    int qrow = qt * 128 + w * 16 + lq;
    short8 qh[2], qlo8[2];
#pragma unroll
    for (int c = 0; c < 2; c++) {
        size_t off = hb + (size_t)qrow * 64 + c * 32 + g * 8;
        qh[c]   = *(const short8*)(qHi + off);
        qlo8[c] = *(const short8*)(qLo + off);
    }
    f32x4 zero = { 0.0f, 0.0f, 0.0f, 0.0f };
    f32x4 acc_o[4];
#pragma unroll
    for (int i = 0; i < 4; i++) acc_o[i] = zero;
    float mrun = -3.0e38f, lrun = 0.0f;
    int ktl = ks ? (qt + 1) : 0;
    int kth = ks ? (2 * qt + 2) : (qt + 1);

#define AT_STAGE(B, KT) do { \
    size_t so = (size_t)(KT) * 4096 + (w * 64 + l) * 8; \
    gload16(kHp + so, &KsH[B][w * 512]); \
    gload16(kLp + so, &KsL[B][w * 512]); \
    gload16(vHp + so, &VsH[B][w * 512]); \
    gload16(vLp + so, &VsL[B][w * 512]); \
} while (0)

#define AT_COMPUTE(B, KT) do { \
    f32x4 sacc[4]; \
    _Pragma("unroll") \
    for (int i = 0; i < 4; i++) sacc[i] = zero; \
    _Pragma("unroll") \
    for (int nf = 0; nf < 4; nf++) { \
        _Pragma("unroll") \
        for (int c = 0; c < 2; c++) { \
            int ka = (nf * 16 + lq) * 64 + (((c * 4 + g) ^ lx) << 3); \
            short8 kh = *(const short8*)&KsH[B][ka]; \
            short8 kl = *(const short8*)&KsL[B][ka]; \
            sacc[nf] = __builtin_amdgcn_mfma_f32_16x16x32_bf16(kh, qh[c], sacc[nf], 0, 0, 0); \
            sacc[nf] = __builtin_amdgcn_mfma_f32_16x16x32_bf16(kh, qlo8[c], sacc[nf], 0, 0, 0); \
            sacc[nf] = __builtin_amdgcn_mfma_f32_16x16x32_bf16(kl, qh[c], sacc[nf], 0, 0, 0); \
        } \
    } \
    _Pragma("unroll") \
    for (int nf = 0; nf < 4; nf++) \
        _Pragma("unroll") \
        for (int r = 0; r < 4; r++) \
            if ((KT) * 64 + nf * 16 + g * 4 + r > qrow) sacc[nf][r] = -1.0e30f; \
    float mt = sacc[0][0]; \
    _Pragma("unroll") \
    for (int nf = 0; nf < 4; nf++) \
        _Pragma("unroll") \
        for (int r = 0; r < 4; r++) mt = fmaxf(mt, sacc[nf][r]); \
    mt = fmaxf(mt, __shfl_xor(mt, 16)); \
    mt = fmaxf(mt, __shfl_xor(mt, 32)); \
    float mnew = fmaxf(mrun, mt); \
    float p[4][4]; \
    float ps = 0.0f; \
    _Pragma("unroll") \
    for (int nf = 0; nf < 4; nf++) \
        _Pragma("unroll") \
        for (int r = 0; r < 4; r++) { \
            float e = __expf(sacc[nf][r] - mnew); \
            p[nf][r] = e; \
            ps += e; \
        } \
    ps += __shfl_xor(ps, 16); \
    ps += __shfl_xor(ps, 32); \
    float scale = __expf(mrun - mnew); \
    lrun = lrun * scale + ps; \
    mrun = mnew; \
    _Pragma("unroll") \
    for (int nf = 0; nf < 4; nf++) { \
        ushort4 ph, pl; \
        bsplit(p[nf][0], ph.x, pl.x); bsplit(p[nf][1], ph.y, pl.y); \
        bsplit(p[nf][2], ph.z, pl.z); bsplit(p[nf][3], ph.w, pl.w); \
        int pa = lq * 64 + (((nf * 2 + (g >> 1)) ^ lx) << 3) + ((g & 1) << 2); \
        *(ushort4*)&PsH[w][pa] = ph; \
        *(ushort4*)&PsL[w][pa] = pl; \
    } \
    float scq[4]; \
    _Pragma("unroll") \
    for (int r = 0; r < 4; r++) scq[r] = __shfl(scale, g * 4 + r); \
    _Pragma("unroll") \
    for (int df = 0; df < 4; df++) \
        _Pragma("unroll") \
        for (int r = 0; r < 4; r++) acc_o[df][r] *= scq[r]; \
    _Pragma("unroll") \
    for (int c = 0; c < 2; c++) { \
        int pa = lq * 64 + (((c * 4 + g) ^ lx) << 3); \
        short8 ph8 = *(const short8*)&PsH[w][pa]; \
        short8 pl8 = *(const short8*)&PsL[w][pa]; \
        _Pragma("unroll") \
        for (int df = 0; df < 4; df++) { \
            int va = (df * 16 + lq) * 64 + (((c * 4 + g) ^ lx) << 3); \
            short8 vh = *(const short8*)&VsH[B][va]; \
            short8 vl = *(const short8*)&VsL[B][va]; \
            acc_o[df] = __builtin_amdgcn_mfma_f32_16x16x32_bf16(ph8, vh, acc_o[df], 0, 0, 0); \
            acc_o[df] = __builtin_amdgcn_mfma_f32_16x16x32_bf16(ph8, vl, acc_o[df], 0, 0, 0); \
            acc_o[df] = __builtin_amdgcn_mfma_f32_16x16x32_bf16(pl8, vh, acc_o[df], 0, 0, 0); \
        } \
    } \
} while (0)

    int kt = ktl;
    AT_STAGE(0, kt);
    for (; kt + 1 < kth; kt += 2) {
        AT_STAGE(1, kt + 1);
        WAIT_VM4;
        BARRIER; SCHEDFENCE;
        AT_COMPUTE(0, kt);
        BARRIER;
        if (kt + 2 < kth) {
            AT_STAGE(0, kt + 2);
            WAIT_VM4;
        } else {
            WAIT_VM0;
        }
        BARRIER; SCHEDFENCE;
        AT_COMPUTE(1, kt + 1);
        BARRIER;
    }
    if (kt < kth) {
        WAIT_VM0;
        BARRIER; SCHEDFENCE;
        AT_COMPUTE(0, kt);
    }
#undef AT_STAGE
#undef AT_COMPUTE

    // partial outputs: m, l per q-row (from g==0 copy) + unnormalized O
    if (g == 0) {
        size_t mi = (size_t)(ks * 32 + bh) * SEQ + (size_t)(qt * 128 + w * 16 + lq);
        mscr[mi] = mrun;
        lscr[mi] = lrun;
    }
#pragma unroll
    for (int df = 0; df < 4; df++)
#pragma unroll
        for (int r = 0; r < 4; r++) {
            size_t row = (size_t)(ks * 32 + bh) * SEQ + (size_t)(qt * 128 + w * 16 + g * 4 + r);
            Opart[row * 64 + df * 16 + lq] = acc_o[df][r];
        }
}

// ---------------- combine KV-split partials -> ao (split-bf16) --------------
__global__ __launch_bounds__(256) void attn_combine_kernel(
    const float* __restrict__ Opart, const float* __restrict__ mscr,
    const float* __restrict__ lscr,
    unsigned short* __restrict__ aoHi, unsigned short* __restrict__ aoLo)
{
    int i = blockIdx.x * 256 + threadIdx.x;   // over 32*1024*16 float4-quads
    int d4 = i & 15;
    int qr = (i >> 4) & (SEQ - 1);
    int bh = i >> 14;
    int b = bh >> 4, h = bh & 15;
    size_t r0 = (size_t)bh * SEQ + qr;
    size_t r1 = (size_t)(32 + bh) * SEQ + qr;
    float m0 = mscr[r0], m1 = mscr[r1];
    float l0 = lscr[r0], l1 = lscr[r1];
    float m = fmaxf(m0, m1);
    float w0 = __expf(m0 - m), w1 = __expf(m1 - m);
    float dn = 1.0f / (w0 * l0 + w1 * l1);
    float4 o0 = *(const float4*)(Opart + r0 * 64 + d4 * 4);
    float4 o1 = *(const float4*)(Opart + r1 * 64 + d4 * 4);
    float4 o;
    o.x = (w0 * o0.x + w1 * o1.x) * dn;
    o.y = (w0 * o0.y + w1 * o1.y) * dn;
    o.z = (w0 * o0.z + w1 * o1.z) * dn;
    o.w = (w0 * o0.w + w1 * o1.w) * dn;
    ushort4 hs, ls;
    bsplit(o.x, hs.x, ls.x); bsplit(o.y, hs.y, ls.y);
    bsplit(o.z, hs.z, ls.z); bsplit(o.w, hs.w, ls.w);
    size_t base = (size_t)b * SEQ * DMODEL + (size_t)qr * DMODEL + h * 64 + d4 * 4;
    *(ushort4*)(aoHi + base) = hs;
    *(ushort4*)(aoLo + base) = ls;
}

// ---------------- gate logits (f32, routing exactness) ----------------------
__global__ __launch_bounds__(256) void gate_kernel(const float* __restrict__ tn2f,
                                                   const float* __restrict__ gw,
                                                   float* __restrict__ logits)
{
    int tok = blockIdx.x;
    int t = threadIdx.x, e = t >> 5, l32 = t & 31;
    const float* xr = tn2f + (size_t)tok * DMODEL;
    const float* gr = gw + (size_t)e * DMODEL;
    float s = 0.0f;
    for (int j = l32; j < DMODEL; j += 32) s += xr[j] * gr[j];
#pragma unroll
    for (int off = 16; off > 0; off >>= 1) s += __shfl_down(s, off, 32);
    if (l32 == 0) logits[tok * NEXP + e] = s;
}

__global__ void zero_kernel(int* p, int n)
{
    int i = blockIdx.x * blockDim.x + threadIdx.x;
    if (i < n) p[i] = 0;
}

// ---------------- top-2 + softmax weights + expert bucketing ----------------
__global__ void top2_kernel(const float* __restrict__ logits, float* __restrict__ rw,
                            int* __restrict__ cnt, int* __restrict__ entry)
{
    int t = blockIdx.x * blockDim.x + threadIdx.x;
    if (t >= T_TOK) return;
    float l[8];
#pragma unroll
    for (int e = 0; e < 8; e++) l[e] = logits[t * 8 + e];
    int e0 = 0;
#pragma unroll
    for (int e = 1; e < 8; e++) if (l[e] > l[e0]) e0 = e;
    int e1 = (e0 == 0) ? 1 : 0;
#pragma unroll
    for (int e = 0; e < 8; e++) if (e != e0 && l[e] > l[e1]) e1 = e;
    float ex = expf(l[e1] - l[e0]);
    float denom = 1.0f + ex;
    rw[t * 2 + 0] = 1.0f / denom;
    rw[t * 2 + 1] = ex / denom;
    int pos = atomicAdd(&cnt[e0], 1);
    entry[e0 * 2048 + pos] = t * 2;
    pos = atomicAdd(&cnt[e1], 1);
    entry[e1 * 2048 + pos] = t * 2 + 1;
}

__global__ void offs_kernel(const int* __restrict__ cnt, int* __restrict__ offs)
{
    if (threadIdx.x == 0) {
        int s = 0;
        for (int e = 0; e < 8; e++) { offs[e] = s; s += cnt[e]; }
    }
}

// ---------------- MoE GEMM1: hid = GELU(tn2h @ f16(w1[e])^T + b1) -----------
// 256x128 tile, 512 thr / 8 waves. Minimum-2-phase schedule: ONE barrier per
// K-step; stage (ds_write B from regs + gload A) issued before compute;
// WAIT_VM2 lets the next B reg-loads span the barrier. Static brA/brB reg
// double-buffer (x2 unrolled). r23 bank swizzle. XCD=expert.
__global__ __launch_bounds__(512) void moe_gemm1_kernel(
    const _Float16* __restrict__ tn2h, const float* __restrict__ w1f,
    const float* __restrict__ b1, const int* __restrict__ cnt, const int* __restrict__ offs,
    const int* __restrict__ entry, _Float16* __restrict__ hid)
{
    int bid = blockIdx.x;
    int e = bid & 7;
    int n_i = (bid >> 3) & 31;
    int m_i = bid >> 8;                   // 0..7
    int ne = cnt[e];
    int m0 = m_i * 256;
    if (m0 >= ne) return;
    int n0 = n_i * 128;
    __shared__ _Float16 As[2][256 * 32];
    __shared__ _Float16 Bs[2][128 * 32];
    int t = threadIdx.x, w = t >> 6, l = t & 63;
    int sa = l >> 2;
    int swz = (l >> 3) & 3;                       // key(row) = (row>>1)&3
    int scA = ((l & 3) ^ swz) * 8;                // pre-swizzled A source col
    int scB = (l & 3) * 8;                        // B source col (floats)
    int rcol = (((l >> 4) ^ ((l >> 1) & 3)) * 8); // swizzled read col
    int g0 = entry[e * 2048 + min(m0 + w * 32 + sa, ne - 1)] >> 1;
    int g1 = entry[e * 2048 + min(m0 + w * 32 + 16 + sa, ne - 1)] >> 1;
    const _Float16* gA0 = tn2h + (size_t)g0 * DMODEL + scA;
    const _Float16* gA1 = tn2h + (size_t)g1 * DMODEL + scA;
    const float* w1e = w1f + (size_t)e * HEXP * DMODEL;
    const float* gB0f = w1e + (size_t)(n0 + w * 16 + sa) * DMODEL + scB;
    const int aoff0 = (w * 32) * 32, aoff1 = (w * 32 + 16) * 32;
    const int boff0 = (w * 16 + sa) * 32 + ((l & 3) ^ swz) * 8;
    int wr = w >> 1, wc = w & 1;
    f32x4 zero = { 0.0f, 0.0f, 0.0f, 0.0f };
    f32x4 acc[4][4];
#pragma unroll
    for (int i = 0; i < 4; i++)
#pragma unroll
        for (int j = 0; j < 4; j++) acc[i][j] = zero;
    f32x4 brA0, brA1, brB0, brB1;

#define M1_WRITEB(B, R0, R1) do { \
    half8 hb = { (_Float16)R0[0], (_Float16)R0[1], (_Float16)R0[2], (_Float16)R0[3], \
                 (_Float16)R1[0], (_Float16)R1[1], (_Float16)R1[2], (_Float16)R1[3] }; \
    *(half8*)&Bs[B][boff0] = hb; \
} while (0)

#define M1_GLOADA(B, K0) do { \
    gload16(gA0 + (K0), &As[B][aoff0]); gload16(gA1 + (K0), &As[B][aoff1]); \
} while (0)

#define M1_COMPUTE(B) do { \
    half8 af[4], bfr[4]; \
    _Pragma("unroll") \
    for (int mi = 0; mi < 4; mi++) \
        af[mi] = *(const half8*)&As[B][(wr * 64 + mi * 16 + (l & 15)) * 32 + rcol]; \
    _Pragma("unroll") \
    for (int ni = 0; ni < 4; ni++) \
        bfr[ni] = *(const half8*)&Bs[B][(wc * 64 + ni * 16 + (l & 15)) * 32 + rcol]; \
    _Pragma("unroll") \
    for (int mi = 0; mi < 4; mi++) \
        _Pragma("unroll") \
        for (int ni = 0; ni < 4; ni++) \
            acc[mi][ni] = __builtin_amdgcn_mfma_f32_16x16x32_f16(af[mi], bfr[ni], acc[mi][ni], 0, 0, 0); \
} while (0)

    const int nt = DMODEL >> 5;            // 32, even
    // prologue: tile 0 staged into buf0; brB preloads tile 1
    brA0 = *(const f32x4*)(gB0f);
    brA1 = *(const f32x4*)(gB0f + 4);
    M1_WRITEB(0, brA0, brA1);
    M1_GLOADA(0, 0);
    brB0 = *(const f32x4*)(gB0f + 32);
    brB1 = *(const f32x4*)(gB0f + 36);
    WAIT_VM2;                              // A(0) landed; brB spans barrier
    BARRIER; SCHEDFENCE;
    for (int kt = 0; kt < nt; kt += 2) {
        // even: stage tile kt+1 (buf1) from brB; compute tile kt (buf0)
        M1_WRITEB(1, brB0, brB1);
        M1_GLOADA(1, (kt + 1) << 5);
        if (kt + 2 < nt) {
            brA0 = *(const f32x4*)(gB0f + ((kt + 2) << 5));
            brA1 = *(const f32x4*)(gB0f + ((kt + 2) << 5) + 4);
        }
        M1_COMPUTE(0);
        if (kt + 2 < nt) { WAIT_VM2; } else { WAIT_VM0; }
        BARRIER; SCHEDFENCE;
        // odd: stage tile kt+2 (buf0) from brA; compute tile kt+1 (buf1)
        if (kt + 2 < nt) {
            M1_WRITEB(0, brA0, brA1);
            M1_GLOADA(0, (kt + 2) << 5);
            if (kt + 3 < nt) {
                brB0 = *(const f32x4*)(gB0f + ((kt + 3) << 5));
                brB1 = *(const f32x4*)(gB0f + ((kt + 3) << 5) + 4);
            }
            M1_COMPUTE(1);
            if (kt + 3 < nt) { WAIT_VM2; } else { WAIT_VM0; }
            BARRIER; SCHEDFENCE;
        } else {
            M1_COMPUTE(1);
        }
    }
#undef M1_WRITEB
#undef M1_GLOADA
#undef M1_COMPUTE

    int off_e = offs[e];
#pragma unroll
    for (int mi = 0; mi < 4; mi++) {
#pragma unroll
        for (int r = 0; r < 4; r++) {
            int row = m0 + wr * 64 + mi * 16 + (l >> 4) * 4 + r;
            if (row < ne) {
                size_t orow = (size_t)(off_e + row) * HEXP;
#pragma unroll
                for (int ni = 0; ni < 4; ni++) {
                    int cg = n0 + wc * 64 + ni * 16 + (l & 15);
                    float v = acc[mi][ni][r] + b1[e * HEXP + cg];
                    hid[orow + cg] = (_Float16)gelu_fast(v);
                }
            }
        }
    }
}

// ---------------- MoE GEMM2: eo = hid @ f16(w2[e])^T (+b2) ------------------
// 256x128 tile, 512 thr / 8 waves, K-split x4. Same minimum-2-phase schedule
// as gemm1 (one barrier/K-step, counted WAIT_VM2, static brA/brB).
// XCD = expert: bid = e + 8*(n_i + 8*(ks + 4*m_i)).
__global__ __launch_bounds__(512) void moe_gemm2_kernel(
    const _Float16* __restrict__ hid, const float* __restrict__ w2f,
    const float* __restrict__ b2, const int* __restrict__ cnt, const int* __restrict__ offs,
    const int* __restrict__ entry,
    float* __restrict__ eoA, float* __restrict__ eoB,
    float* __restrict__ eoC, float* __restrict__ eoD)
{
    int bid = blockIdx.x;
    int e = bid & 7;                      // XCD = expert (balanced: ne ~ equal)
    int rest = bid >> 3;
    int n_i = rest & 7;
    int rest2 = rest >> 3;
    int ks = rest2 & 3;
    int m_i = rest2 >> 2;
    int ne = cnt[e];
    int m0 = m_i * 256;
    if (m0 >= ne) return;
    int n0 = n_i * 128;
    int kbase = ks * (HEXP / 4);
    float* eoP = (ks == 0) ? eoA : (ks == 1) ? eoB : (ks == 2) ? eoC : eoD;
    __shared__ _Float16 As[2][256 * 32];
    __shared__ _Float16 Bs[2][128 * 32];
    int t = threadIdx.x, w = t >> 6, l = t & 63;
    int off_e = offs[e];
    int sa = l >> 2;
    int swz = (l >> 3) & 3;
    int scA = ((l & 3) ^ swz) * 8;
    int scB = (l & 3) * 8;
    int rcol = (((l >> 4) ^ ((l >> 1) & 3)) * 8);
    int r0 = off_e + min(m0 + w * 32 + sa, ne - 1);
    int r1 = off_e + min(m0 + w * 32 + 16 + sa, ne - 1);
    const _Float16* gA0 = hid + (size_t)r0 * HEXP + kbase + scA;
    const _Float16* gA1 = hid + (size_t)r1 * HEXP + kbase + scA;
    const float* w2e = w2f + (size_t)e * DMODEL * HEXP;
    const float* gB0f = w2e + (size_t)(n0 + w * 16 + sa) * HEXP + kbase + scB;
    const int aoff0 = (w * 32) * 32, aoff1 = (w * 32 + 16) * 32;
    const int boff0 = (w * 16 + sa) * 32 + ((l & 3) ^ swz) * 8;
    int wr = w >> 1, wc = w & 1;
    f32x4 zero = { 0.0f, 0.0f, 0.0f, 0.0f };
    f32x4 acc[4][4];
#pragma unroll
    for (int i = 0; i < 4; i++)
#pragma unroll
        for (int j = 0; j < 4; j++) acc[i][j] = zero;
    f32x4 brA0, brA1, brB0, brB1;

#define M2_WRITEB(B, R0, R1) do { \
    half8 hb = { (_Float16)R0[0], (_Float16)R0[1], (_Float16)R0[2], (_Float16)R0[3], \
                 (_Float16)R1[0], (_Float16)R1[1], (_Float16)R1[2], (_Float16)R1[3] }; \
    *(half8*)&Bs[B][boff0] = hb; \
} while (0)

#define M2_GLOADA(B, K0) do { \
    gload16(gA0 + (K0), &As[B][aoff0]); gload16(gA1 + (K0), &As[B][aoff1]); \
} while (0)

#define M2_COMPUTE(B) do { \
    half8 af[4], bfr[4]; \
    _Pragma("unroll") \
    for (int mi = 0; mi < 4; mi++) \
        af[mi] = *(const half8*)&As[B][(wr * 64 + mi * 16 + (l & 15)) * 32 + rcol]; \
    _Pragma("unroll") \
    for (int ni = 0; ni < 4; ni++) \
        bfr[ni] = *(const half8*)&Bs[B][(wc * 64 + ni * 16 + (l & 15)) * 32 + rcol]; \
    _Pragma("unroll") \
    for (int mi = 0; mi < 4; mi++) \
        _Pragma("unroll") \
        for (int ni = 0; ni < 4; ni++) \
            acc[mi][ni] = __builtin_amdgcn_mfma_f32_16x16x32_f16(af[mi], bfr[ni], acc[mi][ni], 0, 0, 0); \
} while (0)

    const int nt = (HEXP / 4) >> 5;        // 32, even
    brA0 = *(const f32x4*)(gB0f);
    brA1 = *(const f32x4*)(gB0f + 4);
    M2_WRITEB(0, brA0, brA1);
    M2_GLOADA(0, 0);
    brB0 = *(const f32x4*)(gB0f + 32);
    brB1 = *(const f32x4*)(gB0f + 36);
    WAIT_VM2;
    BARRIER; SCHEDFENCE;
    for (int kt = 0; kt < nt; kt += 2) {
        M2_WRITEB(1, brB0, brB1);
        M2_GLOADA(1, (kt + 1) << 5);
        if (kt + 2 < nt) {
            brA0 = *(const f32x4*)(gB0f + ((kt + 2) << 5));
            brA1 = *(const f32x4*)(gB0f + ((kt + 2) << 5) + 4);
        }
        M2_COMPUTE(0);
        if (kt + 2 < nt) { WAIT_VM2; } else { WAIT_VM0; }
        BARRIER; SCHEDFENCE;
        if (kt + 2 < nt) {
            M2_WRITEB(0, brA0, brA1);
            M2_GLOADA(0, (kt + 2) << 5);
            if (kt + 3 < nt) {
                brB0 = *(const f32x4*)(gB0f + ((kt + 3) << 5));
                brB1 = *(const f32x4*)(gB0f + ((kt + 3) << 5) + 4);
            }
            M2_COMPUTE(1);
            if (kt + 3 < nt) { WAIT_VM2; } else { WAIT_VM0; }
            BARRIER; SCHEDFENCE;
        } else {
            M2_COMPUTE(1);
        }
    }
#undef M2_WRITEB
#undef M2_GLOADA
#undef M2_COMPUTE

#pragma unroll
    for (int mi = 0; mi < 4; mi++) {
#pragma unroll
        for (int r = 0; r < 4; r++) {
            int row = m0 + wr * 64 + mi * 16 + (l >> 4) * 4 + r;
            if (row < ne) {
                int t2k = entry[e * 2048 + row];
#pragma unroll
                for (int ni = 0; ni < 4; ni++) {
                    int cg = n0 + wc * 64 + ni * 16 + (l & 15);
                    float v = acc[mi][ni][r];
                    if (ks == 0) v += b2[e * DMODEL + cg];
                    eoP[(size_t)t2k * DMODEL + cg] = v;
                }
            }
        }
    }
}

// ---------------- final: out = h + sum_k rw_k * (eoA+eoB+eoC+eoD) -----------
__global__ __launch_bounds__(256) void combine_kernel(const float* __restrict__ hf,
                                                      const float* __restrict__ eoA,
                                                      const float* __restrict__ eoB,
                                                      const float* __restrict__ eoC,
                                                      const float* __restrict__ eoD,
                                                      const float* __restrict__ rw,
                                                      float* __restrict__ out)
{
    int i = blockIdx.x * 256 + threadIdx.x;   // float4 index over 524288
    int tok = i >> 8;
    int d4 = i & 255;
    float4 hv = ((const float4*)hf)[i];
    float p0 = rw[tok * 2], p1 = rw[tok * 2 + 1];
    size_t i0 = (size_t)(tok * 2) * 256 + d4;
    size_t i1 = (size_t)(tok * 2 + 1) * 256 + d4;
    float4 a0 = ((const float4*)eoA)[i0];
    float4 b0 = ((const float4*)eoB)[i0];
    float4 c0 = ((const float4*)eoC)[i0];
    float4 d0 = ((const float4*)eoD)[i0];
    float4 a1 = ((const float4*)eoA)[i1];
    float4 b1 = ((const float4*)eoB)[i1];
    float4 c1 = ((const float4*)eoC)[i1];
    float4 d1 = ((const float4*)eoD)[i1];
    float4 o;
    o.x = hv.x + p0 * (a0.x + b0.x + c0.x + d0.x) + p1 * (a1.x + b1.x + c1.x + d1.x);
    o.y = hv.y + p0 * (a0.y + b0.y + c0.y + d0.y) + p1 * (a1.y + b1.y + c1.y + d1.y);
    o.z = hv.z + p0 * (a0.z + b0.z + c0.z + d0.z) + p1 * (a1.z + b1.z + c1.z + d1.z);
    o.w = hv.w + p0 * (a0.w + b0.w + c0.w + d0.w) + p1 * (a1.w + b1.w + c1.w + d1.w);
    ((float4*)out)[i] = o;
}

// ---------------------------------------------------------------------------
extern "C" void kernel_launch(void* const* d_in, const int* in_sizes, int n_in,
                              void* d_out, int out_size, void* d_ws, size_t ws_size,
                              hipStream_t stream)
{
    const float* x   = (const float*)d_in[0];
    const float* anw = (const float*)d_in[1];
    const float* wq  = (const float*)d_in[2];
    const float* wk  = (const float*)d_in[3];
    const float* wv  = (const float*)d_in[4];
    const float* wo  = (const float*)d_in[5];
    const float* mnw = (const float*)d_in[6];
    const float* gw  = (const float*)d_in[7];
    const float* w1  = (const float*)d_in[8];
    const float* b1  = (const float*)d_in[9];
    const float* w2  = (const float*)d_in[10];
    const float* b2  = (const float*)d_in[11];
    float* out = (float*)d_out;

    char* p = (char*)d_ws;
    auto alloc = [&](size_t bytes) { char* q = p; p += (bytes + 255) & ~(size_t)255; return q; };
    const size_t TD = (size_t)T_TOK * DMODEL;
    unsigned short* tnHi = (unsigned short*)alloc(TD * 2);
    unsigned short* tnLo = (unsigned short*)alloc(TD * 2);
    float*    qf   = (float*)alloc(TD * 4);
    float*    kf   = (float*)alloc(TD * 4);
    float*    vf   = (float*)alloc(TD * 4);
    unsigned short* qHi = (unsigned short*)alloc(TD * 2);
    unsigned short* qLo = (unsigned short*)alloc(TD * 2);
    unsigned short* kHi = (unsigned short*)alloc(TD * 2);
    unsigned short* kLo = (unsigned short*)alloc(TD * 2);
    float*    hf   = (float*)alloc(TD * 4);
    unsigned short* wqH = (unsigned short*)alloc((size_t)DMODEL * DMODEL * 2);
    unsigned short* wqL = (unsigned short*)alloc((size_t)DMODEL * DMODEL * 2);
    unsigned short* wkH = (unsigned short*)alloc((size_t)DMODEL * DMODEL * 2);
    unsigned short* wkL = (unsigned short*)alloc((size_t)DMODEL * DMODEL * 2);
    unsigned short* wvH = (unsigned short*)alloc((size_t)DMODEL * DMODEL * 2);
    unsigned short* wvL = (unsigned short*)alloc((size_t)DMODEL * DMODEL * 2);
    unsigned short* woH = (unsigned short*)alloc((size_t)DMODEL * DMODEL * 2);
    unsigned short* woL = (unsigned short*)alloc((size_t)DMODEL * DMODEL * 2);
    char*     moescr = alloc((size_t)64 * 1024 * 1024);   // Opart / eoC / eoD
    _Float16* hid  = (_Float16*)alloc((size_t)4096 * HEXP * 2);
    float*    logits = (float*)alloc((size_t)T_TOK * NEXP * 4);
    float*    rw   = (float*)alloc((size_t)T_TOK * 2 * 4);
    int*      cnt  = (int*)alloc(256);
    int*      offs = (int*)alloc(256);
    int*      entry = (int*)alloc((size_t)NEXP * 2048 * 4);
    float*    mscr = (float*)alloc((size_t)2 * 32 * SEQ * 4);
    float*    lscr = (float*)alloc((size_t)2 * 32 * SEQ * 4);
    (void)ws_size; (void)in_sizes; (void)n_in; (void)out_size;

    // aliases (lifetimes): qf dead after rope -> vtHi/vtLo (dead after attn) -> tn2f
    unsigned short* vtHi = (unsigned short*)qf;
    unsigned short* vtLo = (unsigned short*)qf + TD;
    float* tn2f = qf;
    // kf dead after rope -> aoHi/aoLo
    unsigned short* aoHi = (unsigned short*)kf;
    unsigned short* aoLo = (unsigned short*)kf + TD;
    // vf dead after vtrans -> tn2h
    _Float16* tn2h = (_Float16*)vf;
    // qHi..kLo (16MB contiguous, dead after attn) -> eoA
    float* eoA = (float*)qHi;
    // wqH..woL (16MB contiguous, dead after O-proj) -> eoB
    float* eoB = (float*)wqH;
    // moescr (64MB): [0,16.8MB) attn Opart (dead after attn_combine);
    // [32MB,48MB) eoC, [48MB,64MB) eoD — written by gemm2, read by combine.
    float* Opart = (float*)moescr;
    float* eoC = (float*)(moescr + (size_t)32 * 1024 * 1024);
    float* eoD = (float*)(moescr + (size_t)48 * 1024 * 1024);

    // attention weight splits (one fused launch)
    split4_kernel<<<dim3(512, 4), 256, 0, stream>>>(wq, wk, wv, wo,
        wqH, wkH, wvH, woH, wqL, wkL, wvL, woL, DMODEL * DMODEL / 4);

    // attention path (split-bf16 MFMA end-to-end)
    rmsnorm_kernel<<<T_TOK, 256, 0, stream>>>(x, anw, nullptr, (_Float16*)nullptr, tnHi, tnLo);
    gemm_split_kernel<<<dim3(16, 16, 3), 256, 0, stream>>>(
        tnHi, tnLo, wqH, wqL, wkH, wkL, wvH, wvL, qf, kf, vf, nullptr, DMODEL);
    rope_split_kernel<<<4096, 256, 0, stream>>>(qf, kf, qHi, qLo, kHi, kLo);
    vtrans_kernel<<<dim3(16, 32), 256, 0, stream>>>(vf, vtHi, vtLo);
    attn_mfma_kernel<<<dim3(8, 32, 2), 512, 0, stream>>>(qHi, qLo, kHi, kLo, vtHi, vtLo,
                                                         Opart, mscr, lscr);
    attn_combine_kernel<<<2048, 256, 0, stream>>>(Opart, mscr, lscr, aoHi, aoLo);
    gemm_split_kernel<<<dim3(16, 16, 1), 256, 0, stream>>>(
        aoHi, aoLo, woH, woL, woH, woL, woH, woL, hf, hf, hf, x, DMODEL);

    // MoE (no weight casts: gemm1/gemm2 read f32 weights directly)
    rmsnorm_kernel<<<T_TOK, 256, 0, stream>>>(hf, mnw, tn2f, tn2h, nullptr, nullptr);
    gate_kernel<<<T_TOK, 256, 0, stream>>>(tn2f, gw, logits);
    zero_kernel<<<1, 64, 0, stream>>>(cnt, 8);
    top2_kernel<<<8, 256, 0, stream>>>(logits, rw, cnt, entry);
    offs_kernel<<<1, 1, 0, stream>>>(cnt, offs);
    moe_gemm1_kernel<<<2048, 512, 0, stream>>>(tn2h, w1, b1, cnt, offs, entry, hid);
    moe_gemm2_kernel<<<2048, 512, 0, stream>>>(hid, w2, b2, cnt, offs, entry,
                                               eoA, eoB, eoC, eoD);
    combine_kernel<<<2048, 256, 0, stream>>>(hf, eoA, eoB, eoC, eoD, rw, out);
}

// Round 27
// 384.759 us; speedup vs baseline: 1.1710x; 1.1710x over previous
//
#include <hip/hip_runtime.h>
#include <hip/hip_bf16.h>
#include <hip/hip_fp16.h>

// ---------------------------------------------------------------------------
// DattaBot block: RMSNorm -> QKV -> RoPE -> causal attn -> O-proj+res ->
//                 RMSNorm -> top2/8 MoE (GELU, H=4096) -> res
// Round 27: revert to r23 (400.4 best; r24-26 structural experiments all
// regressed via residency loss). Single lever: gemm2's K-split partials
// (eoA..eoD) stored as f16 instead of f32 -> halves 134MB of eo HBM traffic
// (gemm2 writes + combine reads). Occupancy/schedule untouched.
// ---------------------------------------------------------------------------

#define T_TOK 2048
#define DMODEL 1024
#define SEQ 1024
#define NEXP 8
#define HEXP 4096

typedef __attribute__((ext_vector_type(4))) float f32x4;
typedef __attribute__((ext_vector_type(4))) int i32x4;
typedef __attribute__((ext_vector_type(8))) short short8;      // 8 bf16
typedef __attribute__((ext_vector_type(8))) _Float16 half8;
typedef __attribute__((ext_vector_type(4))) _Float16 half4;

#define WAIT_VM3 asm volatile("s_waitcnt vmcnt(3)" ::: "memory")
#define WAIT_VM4 asm volatile("s_waitcnt vmcnt(4)" ::: "memory")
#define WAIT_VM6 asm volatile("s_waitcnt vmcnt(6)" ::: "memory")
#define WAIT_VM0 asm volatile("s_waitcnt vmcnt(0)" ::: "memory")
#define WAIT_LGKM0 asm volatile("s_waitcnt lgkmcnt(0)" ::: "memory")
#define BARRIER __builtin_amdgcn_s_barrier()
#define SCHEDFENCE __builtin_amdgcn_sched_barrier(0)

// async global->LDS, 16B per lane. LDS dest is wave-uniform base + lane*16;
// global src is per-lane (gather-capable).
__device__ __forceinline__ void gload16(const void* g, void* l)
{
    __builtin_amdgcn_global_load_lds((const __attribute__((address_space(1))) void*)g,
                                     (__attribute__((address_space(3))) void*)l, 16, 0, 0);
}

// split f32 -> bf16 hi + bf16 lo (round-nearest-even both)
__device__ __forceinline__ void bsplit(float f, unsigned short& hi, unsigned short& lo)
{
    unsigned int u = __float_as_uint(f);
    unsigned int rh = (u + 0x7FFFu + ((u >> 16) & 1u)) >> 16;
    hi = (unsigned short)rh;
    float fl = f - __uint_as_float(rh << 16);
    unsigned int u2 = __float_as_uint(fl);
    lo = (unsigned short)((u2 + 0x7FFFu + ((u2 >> 16) & 1u)) >> 16);
}

// tanh-form GELU (max dev from erf-GELU ~3e-4; cheaper than erff by ~3x)
__device__ __forceinline__ float gelu_fast(float v)
{
    float e = __expf(-1.5957691216f * v * (1.0f + 0.044715f * v * v));
    return v * __builtin_amdgcn_rcpf(1.0f + e);
}

// ---------------- split 4 weight matrices f32 -> bf16 hi/lo -----------------
__global__ __launch_bounds__(256) void split4_kernel(
    const float* __restrict__ s0, const float* __restrict__ s1,
    const float* __restrict__ s2, const float* __restrict__ s3,
    unsigned short* __restrict__ h0, unsigned short* __restrict__ h1,
    unsigned short* __restrict__ h2, unsigned short* __restrict__ h3,
    unsigned short* __restrict__ l0, unsigned short* __restrict__ l1,
    unsigned short* __restrict__ l2, unsigned short* __restrict__ l3, int n4)
{
    int z = blockIdx.y;
    const float* src = (z == 0) ? s0 : (z == 1) ? s1 : (z == 2) ? s2 : s3;
    unsigned short* hi = (z == 0) ? h0 : (z == 1) ? h1 : (z == 2) ? h2 : h3;
    unsigned short* lo = (z == 0) ? l0 : (z == 1) ? l1 : (z == 2) ? l2 : l3;
    int stride = gridDim.x * blockDim.x;
    for (int i = blockIdx.x * blockDim.x + threadIdx.x; i < n4; i += stride) {
        float4 v = ((const float4*)src)[i];
        ushort4 h, l;
        bsplit(v.x, h.x, l.x); bsplit(v.y, h.y, l.y);
        bsplit(v.z, h.z, l.z); bsplit(v.w, h.w, l.w);
        *(ushort4*)(hi + (size_t)i * 4) = h;
        *(ushort4*)(lo + (size_t)i * 4) = l;
    }
}

// ---------------- RMSNorm: f32 out / f16 out / bf16-split out (optional) ----
__global__ __launch_bounds__(256) void rmsnorm_kernel(const float* __restrict__ x,
                                                      const float* __restrict__ w,
                                                      float* __restrict__ of,
                                                      _Float16* __restrict__ oh,
                                                      unsigned short* __restrict__ ohi,
                                                      unsigned short* __restrict__ olo)
{
    int row = blockIdx.x;
    int t = threadIdx.x;
    float4 v = ((const float4*)(x + (size_t)row * DMODEL))[t];
    float ss = v.x * v.x + v.y * v.y + v.z * v.z + v.w * v.w;
#pragma unroll
    for (int off = 32; off > 0; off >>= 1) ss += __shfl_xor(ss, off);
    __shared__ float red[4];
    if ((t & 63) == 0) red[t >> 6] = ss;
    __syncthreads();
    float tot = red[0] + red[1] + red[2] + red[3];
    float sc = rsqrtf(tot * (1.0f / DMODEL) + 1e-6f);
    float4 w4 = ((const float4*)w)[t];
    float4 o;
    o.x = v.x * sc * w4.x; o.y = v.y * sc * w4.y; o.z = v.z * sc * w4.z; o.w = v.w * sc * w4.w;
    if (of) ((float4*)(of + (size_t)row * DMODEL))[t] = o;
    if (oh) {
        half4 h = { (_Float16)o.x, (_Float16)o.y, (_Float16)o.z, (_Float16)o.w };
        *(half4*)(oh + (size_t)row * DMODEL + t * 4) = h;
    }
    if (ohi) {
        ushort4 h, l;
        bsplit(o.x, h.x, l.x); bsplit(o.y, h.y, l.y);
        bsplit(o.z, h.z, l.z); bsplit(o.w, h.w, l.w);
        *(ushort4*)(ohi + (size_t)row * DMODEL + t * 4) = h;
        *(ushort4*)(olo + (size_t)row * DMODEL + t * 4) = l;
    }
}

// ---------------- split-bf16 GEMM: C = A*B^T (+resid), 3-term MFMA ----------
// 128x64 tile, BK=32, 2-buffer pipeline with counted vmcnt (6 loads/stage).
__global__ __launch_bounds__(256) void gemm_split_kernel(
    const unsigned short* __restrict__ aH, const unsigned short* __restrict__ aL,
    const unsigned short* __restrict__ b0H, const unsigned short* __restrict__ b0L,
    const unsigned short* __restrict__ b1H, const unsigned short* __restrict__ b1L,
    const unsigned short* __restrict__ b2H, const unsigned short* __restrict__ b2L,
    float* __restrict__ C0, float* __restrict__ C1, float* __restrict__ C2,
    const float* __restrict__ resid, int K)
{
    const unsigned short* bH = (blockIdx.z == 0) ? b0H : (blockIdx.z == 1 ? b1H : b2H);
    const unsigned short* bL = (blockIdx.z == 0) ? b0L : (blockIdx.z == 1 ? b1L : b2L);
    float* C = (blockIdx.z == 0) ? C0 : (blockIdx.z == 1 ? C1 : C2);
    int m0 = blockIdx.y * 128, n0 = blockIdx.x * 64;
    __shared__ unsigned short AsH[2][128 * 32];
    __shared__ unsigned short AsL[2][128 * 32];
    __shared__ unsigned short BsH[2][64 * 32];
    __shared__ unsigned short BsL[2][64 * 32];
    int t = threadIdx.x, w = t >> 6, l = t & 63;
    int sa = l >> 2, sc = (l & 3) * 8;
    const unsigned short* gAH0 = aH + (size_t)(m0 + w * 32 + sa) * K + sc;
    const unsigned short* gAH1 = aH + (size_t)(m0 + w * 32 + 16 + sa) * K + sc;
    const unsigned short* gAL0 = aL + (size_t)(m0 + w * 32 + sa) * K + sc;
    const unsigned short* gAL1 = aL + (size_t)(m0 + w * 32 + 16 + sa) * K + sc;
    const unsigned short* gBH0 = bH + (size_t)(n0 + w * 16 + sa) * K + sc;
    const unsigned short* gBL0 = bL + (size_t)(n0 + w * 16 + sa) * K + sc;
    const int aoff0 = (w * 32) * 32;
    const int aoff1 = (w * 32 + 16) * 32;
    const int boff0 = (w * 16) * 32;
    int wr = w >> 1, wc = w & 1;
    f32x4 zero = { 0.0f, 0.0f, 0.0f, 0.0f };
    f32x4 acc[4][2];
#pragma unroll
    for (int i = 0; i < 4; i++)
#pragma unroll
        for (int j = 0; j < 2; j++) acc[i][j] = zero;

#define GS_STAGE(B, K0) do { \
    gload16(gAH0 + (K0), &AsH[B][aoff0]); gload16(gAH1 + (K0), &AsH[B][aoff1]); \
    gload16(gAL0 + (K0), &AsL[B][aoff0]); gload16(gAL1 + (K0), &AsL[B][aoff1]); \
    gload16(gBH0 + (K0), &BsH[B][boff0]); gload16(gBL0 + (K0), &BsL[B][boff0]); \
} while (0)

#define GS_COMPUTE(B) do { \
    short8 ah[4], al[4], bh8[2], bl8[2]; \
    _Pragma("unroll") \
    for (int mi = 0; mi < 4; mi++) { \
        int base = (wr * 64 + mi * 16 + (l & 15)) * 32 + (l >> 4) * 8; \
        ah[mi] = *(const short8*)&AsH[B][base]; \
        al[mi] = *(const short8*)&AsL[B][base]; } \
    _Pragma("unroll") \
    for (int ni = 0; ni < 2; ni++) { \
        int base = (wc * 32 + ni * 16 + (l & 15)) * 32 + (l >> 4) * 8; \
        bh8[ni] = *(const short8*)&BsH[B][base]; \
        bl8[ni] = *(const short8*)&BsL[B][base]; } \
    _Pragma("unroll") \
    for (int mi = 0; mi < 4; mi++) \
        _Pragma("unroll") \
        for (int ni = 0; ni < 2; ni++) { \
            acc[mi][ni] = __builtin_amdgcn_mfma_f32_16x16x32_bf16(ah[mi], bh8[ni], acc[mi][ni], 0, 0, 0); \
            acc[mi][ni] = __builtin_amdgcn_mfma_f32_16x16x32_bf16(ah[mi], bl8[ni], acc[mi][ni], 0, 0, 0); \
            acc[mi][ni] = __builtin_amdgcn_mfma_f32_16x16x32_bf16(al[mi], bh8[ni], acc[mi][ni], 0, 0, 0); } \
} while (0)

    const int nt = K >> 5;                 // always even (K = 1024)
    GS_STAGE(0, 0);
    for (int kt = 0; kt < nt; kt += 2) {
        GS_STAGE(1, (kt + 1) << 5);
        WAIT_VM6;
        BARRIER; SCHEDFENCE;
        GS_COMPUTE(0);
        BARRIER;
        if (kt + 2 < nt) {
            GS_STAGE(0, (kt + 2) << 5);
            WAIT_VM6;
        } else {
            WAIT_VM0;
        }
        BARRIER; SCHEDFENCE;
        GS_COMPUTE(1);
        BARRIER;
    }
#undef GS_STAGE
#undef GS_COMPUTE

#pragma unroll
    for (int mi = 0; mi < 4; mi++) {
#pragma unroll
        for (int r = 0; r < 4; r++) {
            int row = m0 + wr * 64 + mi * 16 + (l >> 4) * 4 + r;
#pragma unroll
            for (int ni = 0; ni < 2; ni++) {
                int col = n0 + wc * 32 + ni * 16 + (l & 15);
                float v = acc[mi][ni][r];
                if (resid) v += resid[(size_t)row * DMODEL + col];
                C[(size_t)row * DMODEL + col] = v;
            }
        }
    }
}

// ---------------- fused RoPE + split --------------------------------------
// Q out: head-major linear [bh][s][64]. K out: 64-row tiles, XOR-swizzled
// (slot' = slot ^ (row&7)) so attn can gload16 linearly + ds_read swizzled.
__global__ __launch_bounds__(256) void rope_split_kernel(
    const float* __restrict__ qf, const float* __restrict__ kf,
    unsigned short* __restrict__ qHi, unsigned short* __restrict__ qLo,
    unsigned short* __restrict__ kHi, unsigned short* __restrict__ kLo)
{
    int i = blockIdx.x * 256 + threadIdx.x;   // 2048*16*32
    int tok = i >> 9;
    int r = i & 511;
    int hh = r >> 5, ii = r & 31;
    int s = tok & (SEQ - 1);
    int b = tok >> 10;
    float invf = powf(10000.0f, -(float)(2 * ii) * (1.0f / 64.0f));
    float ang = (float)s * invf;
    float c = cosf(ang), sn = sinf(ang);
    size_t base = (size_t)tok * DMODEL + hh * 64 + ii;
    float q1 = qf[base], q2 = qf[base + 32];
    float k1 = kf[base], k2 = kf[base + 32];
    float rq1 = (q1 * c - q2 * sn) * 0.125f;
    float rq2 = (q2 * c + q1 * sn) * 0.125f;
    float rk1 = k1 * c - k2 * sn;
    float rk2 = k2 * c + k1 * sn;
    int bh = b * 16 + hh;
    // Q: linear head-major
    size_t qb = ((size_t)bh * SEQ + s) * 64 + ii;
    unsigned short h, lo;
    bsplit(rq1, h, lo); qHi[qb] = h; qLo[qb] = lo;
    bsplit(rq2, h, lo); qHi[qb + 32] = h; qLo[qb + 32] = lo;
    // K: swizzled tiles [bh][s>>6][row=s&63][swz(d)]
    size_t kb = (size_t)bh * (SEQ * 64) + (size_t)(s >> 6) * 4096 + (size_t)(s & 63) * 64;
    int d1 = ii, d2 = ii + 32;
    int p1 = (((d1 >> 3) ^ (s & 7)) << 3) | (d1 & 7);
    int p2 = (((d2 >> 3) ^ (s & 7)) << 3) | (d2 & 7);
    bsplit(rk1, h, lo); kHi[kb + p1] = h; kLo[kb + p1] = lo;
    bsplit(rk2, h, lo); kHi[kb + p2] = h; kLo[kb + p2] = lo;
}

// ---------------- V transpose+split: -> vt[bh][kt][row=d][swz(scol)] --------
__global__ __launch_bounds__(256) void vtrans_kernel(const float* __restrict__ vf,
                                                     unsigned short* __restrict__ vtHi,
                                                     unsigned short* __restrict__ vtLo)
{
    int sb = blockIdx.x, bh = blockIdx.y;
    int b = bh >> 4, h = bh & 15;
    __shared__ unsigned short tH[64][72];
    __shared__ unsigned short tL[64][72];
    int t = threadIdx.x;
#pragma unroll
    for (int i = 0; i < 4; i++) {
        int idx = i * 256 + t, row = idx >> 4, c4 = idx & 15;
        float4 v = *(const float4*)(vf + (size_t)(b * SEQ + sb * 64 + row) * DMODEL + h * 64 + c4 * 4);
        unsigned short hh, ll;
        bsplit(v.x, hh, ll); tH[c4 * 4 + 0][row] = hh; tL[c4 * 4 + 0][row] = ll;
        bsplit(v.y, hh, ll); tH[c4 * 4 + 1][row] = hh; tL[c4 * 4 + 1][row] = ll;
        bsplit(v.z, hh, ll); tH[c4 * 4 + 2][row] = hh; tL[c4 * 4 + 2][row] = ll;
        bsplit(v.w, hh, ll); tH[c4 * 4 + 3][row] = hh; tL[c4 * 4 + 3][row] = ll;
    }
    __syncthreads();
#pragma unroll
    for (int i = 0; i < 4; i++) {
        int idx = i * 256 + t, d = idx >> 4, sc4 = idx & 15;
        ushort4 oh = { tH[d][sc4 * 4 + 0], tH[d][sc4 * 4 + 1], tH[d][sc4 * 4 + 2], tH[d][sc4 * 4 + 3] };
        ushort4 ol = { tL[d][sc4 * 4 + 0], tL[d][sc4 * 4 + 1], tL[d][sc4 * 4 + 2], tL[d][sc4 * 4 + 3] };
        size_t off = (size_t)bh * (64 * SEQ) + (size_t)sb * 4096 + (size_t)d * 64
                   + (((sc4 >> 1) ^ (d & 7)) << 3) + ((sc4 & 1) << 2);
        *(ushort4*)(vtHi + off) = oh;
        *(ushort4*)(vtLo + off) = ol;
    }
}

// ---------------- MFMA flash attention (split-bf16, causal, KV-split x2) ----
// 8 waves, 128 q-rows/block. K/V tiles staged via global_load_lds (counted
// vmcnt pipeline); swizzled frag reads.
__global__ __launch_bounds__(512) void attn_mfma_kernel(
    const unsigned short* __restrict__ qHi, const unsigned short* __restrict__ qLo,
    const unsigned short* __restrict__ kHi, const unsigned short* __restrict__ kLo,
    const unsigned short* __restrict__ vtHi, const unsigned short* __restrict__ vtLo,
    float* __restrict__ Opart, float* __restrict__ mscr, float* __restrict__ lscr)
{
    int qt = 7 - blockIdx.x;               // reversed: biggest blocks first
    int bh = blockIdx.y, ks = blockIdx.z;
    int t = threadIdx.x, w = t >> 6, l = t & 63;
    int lq = l & 15, g = l >> 4, lx = lq & 7;
    __shared__ unsigned short KsH[2][4096];
    __shared__ unsigned short KsL[2][4096];
    __shared__ unsigned short VsH[2][4096];
    __shared__ unsigned short VsL[2][4096];
    __shared__ unsigned short PsH[8][1024];
    __shared__ unsigned short PsL[8][1024];
    const size_t hb = (size_t)bh * (SEQ * 64);
    const unsigned short* kHp = kHi + hb;
    const unsigned short* kLp = kLo + hb;
    const unsigned short* vHp = vtHi + hb;
    const unsigned short* vLp = vtLo + hb;
    int qrow = qt * 128 + w * 16 + lq;
    short8 qh[2], qlo8[2];
#pragma unroll
    for (int c = 0; c < 2; c++) {
        size_t off = hb + (size_t)qrow * 64 + c * 32 + g * 8;
        qh[c]   = *(const short8*)(qHi + off);
        qlo8[c] = *(const short8*)(qLo + off);
    }
    f32x4 zero = { 0.0f, 0.0f, 0.0f, 0.0f };
    f32x4 acc_o[4];
#pragma unroll
    for (int i = 0; i < 4; i++) acc_o[i] = zero;
    float mrun = -3.0e38f, lrun = 0.0f;
    int ktl = ks ? (qt + 1) : 0;
    int kth = ks ? (2 * qt + 2) : (qt + 1);

#define AT_STAGE(B, KT) do { \
    size_t so = (size_t)(KT) * 4096 + (w * 64 + l) * 8; \
    gload16(kHp + so, &KsH[B][w * 512]); \
    gload16(kLp + so, &KsL[B][w * 512]); \
    gload16(vHp + so, &VsH[B][w * 512]); \
    gload16(vLp + so, &VsL[B][w * 512]); \
} while (0)

#define AT_COMPUTE(B, KT) do { \
    f32x4 sacc[4]; \
    _Pragma("unroll") \
    for (int i = 0; i < 4; i++) sacc[i] = zero; \
    _Pragma("unroll") \
    for (int nf = 0; nf < 4; nf++) { \
        _Pragma("unroll") \
        for (int c = 0; c < 2; c++) { \
            int ka = (nf * 16 + lq) * 64 + (((c * 4 + g) ^ lx) << 3); \
            short8 kh = *(const short8*)&KsH[B][ka]; \
            short8 kl = *(const short8*)&KsL[B][ka]; \
            sacc[nf] = __builtin_amdgcn_mfma_f32_16x16x32_bf16(kh, qh[c], sacc[nf], 0, 0, 0); \
            sacc[nf] = __builtin_amdgcn_mfma_f32_16x16x32_bf16(kh, qlo8[c], sacc[nf], 0, 0, 0); \
            sacc[nf] = __builtin_amdgcn_mfma_f32_16x16x32_bf16(kl, qh[c], sacc[nf], 0, 0, 0); \
        } \
    } \
    _Pragma("unroll") \
    for (int nf = 0; nf < 4; nf++) \
        _Pragma("unroll") \
        for (int r = 0; r < 4; r++) \
            if ((KT) * 64 + nf * 16 + g * 4 + r > qrow) sacc[nf][r] = -1.0e30f; \
    float mt = sacc[0][0]; \
    _Pragma("unroll") \
    for (int nf = 0; nf < 4; nf++) \
        _Pragma("unroll") \
        for (int r = 0; r < 4; r++) mt = fmaxf(mt, sacc[nf][r]); \
    mt = fmaxf(mt, __shfl_xor(mt, 16)); \
    mt = fmaxf(mt, __shfl_xor(mt, 32)); \
    float mnew = fmaxf(mrun, mt); \
    float p[4][4]; \
    float ps = 0.0f; \
    _Pragma("unroll") \
    for (int nf = 0; nf < 4; nf++) \
        _Pragma("unroll") \
        for (int r = 0; r < 4; r++) { \
            float e = __expf(sacc[nf][r] - mnew); \
            p[nf][r] = e; \
            ps += e; \
        } \
    ps += __shfl_xor(ps, 16); \
    ps += __shfl_xor(ps, 32); \
    float scale = __expf(mrun - mnew); \
    lrun = lrun * scale + ps; \
    mrun = mnew; \
    _Pragma("unroll") \
    for (int nf = 0; nf < 4; nf++) { \
        ushort4 ph, pl; \
        bsplit(p[nf][0], ph.x, pl.x); bsplit(p[nf][1], ph.y, pl.y); \
        bsplit(p[nf][2], ph.z, pl.z); bsplit(p[nf][3], ph.w, pl.w); \
        int pa = lq * 64 + (((nf * 2 + (g >> 1)) ^ lx) << 3) + ((g & 1) << 2); \
        *(ushort4*)&PsH[w][pa] = ph; \
        *(ushort4*)&PsL[w][pa] = pl; \
    } \
    float scq[4]; \
    _Pragma("unroll") \
    for (int r = 0; r < 4; r++) scq[r] = __shfl(scale, g * 4 + r); \
    _Pragma("unroll") \
    for (int df = 0; df < 4; df++) \
        _Pragma("unroll") \
        for (int r = 0; r < 4; r++) acc_o[df][r] *= scq[r]; \
    _Pragma("unroll") \
    for (int c = 0; c < 2; c++) { \
        int pa = lq * 64 + (((c * 4 + g) ^ lx) << 3); \
        short8 ph8 = *(const short8*)&PsH[w][pa]; \
        short8 pl8 = *(const short8*)&PsL[w][pa]; \
        _Pragma("unroll") \
        for (int df = 0; df < 4; df++) { \
            int va = (df * 16 + lq) * 64 + (((c * 4 + g) ^ lx) << 3); \
            short8 vh = *(const short8*)&VsH[B][va]; \
            short8 vl = *(const short8*)&VsL[B][va]; \
            acc_o[df] = __builtin_amdgcn_mfma_f32_16x16x32_bf16(ph8, vh, acc_o[df], 0, 0, 0); \
            acc_o[df] = __builtin_amdgcn_mfma_f32_16x16x32_bf16(ph8, vl, acc_o[df], 0, 0, 0); \
            acc_o[df] = __builtin_amdgcn_mfma_f32_16x16x32_bf16(pl8, vh, acc_o[df], 0, 0, 0); \
        } \
    } \
} while (0)

    int kt = ktl;
    AT_STAGE(0, kt);
    for (; kt + 1 < kth; kt += 2) {
        AT_STAGE(1, kt + 1);
        WAIT_VM4;
        BARRIER; SCHEDFENCE;
        AT_COMPUTE(0, kt);
        BARRIER;
        if (kt + 2 < kth) {
            AT_STAGE(0, kt + 2);
            WAIT_VM4;
        } else {
            WAIT_VM0;
        }
        BARRIER; SCHEDFENCE;
        AT_COMPUTE(1, kt + 1);
        BARRIER;
    }
    if (kt < kth) {
        WAIT_VM0;
        BARRIER; SCHEDFENCE;
        AT_COMPUTE(0, kt);
    }
#undef AT_STAGE
#undef AT_COMPUTE

    // partial outputs: m, l per q-row (from g==0 copy) + unnormalized O
    if (g == 0) {
        size_t mi = (size_t)(ks * 32 + bh) * SEQ + (size_t)(qt * 128 + w * 16 + lq);
        mscr[mi] = mrun;
        lscr[mi] = lrun;
    }
#pragma unroll
    for (int df = 0; df < 4; df++)
#pragma unroll
        for (int r = 0; r < 4; r++) {
            size_t row = (size_t)(ks * 32 + bh) * SEQ + (size_t)(qt * 128 + w * 16 + g * 4 + r);
            Opart[row * 64 + df * 16 + lq] = acc_o[df][r];
        }
}

// ---------------- combine KV-split partials -> ao (split-bf16) --------------
__global__ __launch_bounds__(256) void attn_combine_kernel(
    const float* __restrict__ Opart, const float* __restrict__ mscr,
    const float* __restrict__ lscr,
    unsigned short* __restrict__ aoHi, unsigned short* __restrict__ aoLo)
{
    int i = blockIdx.x * 256 + threadIdx.x;   // over 32*1024*16 float4-quads
    int d4 = i & 15;
    int qr = (i >> 4) & (SEQ - 1);
    int bh = i >> 14;
    int b = bh >> 4, h = bh & 15;
    size_t r0 = (size_t)bh * SEQ + qr;
    size_t r1 = (size_t)(32 + bh) * SEQ + qr;
    float m0 = mscr[r0], m1 = mscr[r1];
    float l0 = lscr[r0], l1 = lscr[r1];
    float m = fmaxf(m0, m1);
    float w0 = __expf(m0 - m), w1 = __expf(m1 - m);
    float dn = 1.0f / (w0 * l0 + w1 * l1);
    float4 o0 = *(const float4*)(Opart + r0 * 64 + d4 * 4);
    float4 o1 = *(const float4*)(Opart + r1 * 64 + d4 * 4);
    float4 o;
    o.x = (w0 * o0.x + w1 * o1.x) * dn;
    o.y = (w0 * o0.y + w1 * o1.y) * dn;
    o.z = (w0 * o0.z + w1 * o1.z) * dn;
    o.w = (w0 * o0.w + w1 * o1.w) * dn;
    ushort4 hs, ls;
    bsplit(o.x, hs.x, ls.x); bsplit(o.y, hs.y, ls.y);
    bsplit(o.z, hs.z, ls.z); bsplit(o.w, hs.w, ls.w);
    size_t base = (size_t)b * SEQ * DMODEL + (size_t)qr * DMODEL + h * 64 + d4 * 4;
    *(ushort4*)(aoHi + base) = hs;
    *(ushort4*)(aoLo + base) = ls;
}

// ---------------- gate logits (f32, routing exactness) ----------------------
__global__ __launch_bounds__(256) void gate_kernel(const float* __restrict__ tn2f,
                                                   const float* __restrict__ gw,
                                                   float* __restrict__ logits)
{
    int tok = blockIdx.x;
    int t = threadIdx.x, e = t >> 5, l32 = t & 31;
    const float* xr = tn2f + (size_t)tok * DMODEL;
    const float* gr = gw + (size_t)e * DMODEL;
    float s = 0.0f;
    for (int j = l32; j < DMODEL; j += 32) s += xr[j] * gr[j];
#pragma unroll
    for (int off = 16; off > 0; off >>= 1) s += __shfl_down(s, off, 32);
    if (l32 == 0) logits[tok * NEXP + e] = s;
}

__global__ void zero_kernel(int* p, int n)
{
    int i = blockIdx.x * blockDim.x + threadIdx.x;
    if (i < n) p[i] = 0;
}

// ---------------- top-2 + softmax weights + expert bucketing ----------------
__global__ void top2_kernel(const float* __restrict__ logits, float* __restrict__ rw,
                            int* __restrict__ cnt, int* __restrict__ entry)
{
    int t = blockIdx.x * blockDim.x + threadIdx.x;
    if (t >= T_TOK) return;
    float l[8];
#pragma unroll
    for (int e = 0; e < 8; e++) l[e] = logits[t * 8 + e];
    int e0 = 0;
#pragma unroll
    for (int e = 1; e < 8; e++) if (l[e] > l[e0]) e0 = e;
    int e1 = (e0 == 0) ? 1 : 0;
#pragma unroll
    for (int e = 0; e < 8; e++) if (e != e0 && l[e] > l[e1]) e1 = e;
    float ex = expf(l[e1] - l[e0]);
    float denom = 1.0f + ex;
    rw[t * 2 + 0] = 1.0f / denom;
    rw[t * 2 + 1] = ex / denom;
    int pos = atomicAdd(&cnt[e0], 1);
    entry[e0 * 2048 + pos] = t * 2;
    pos = atomicAdd(&cnt[e1], 1);
    entry[e1 * 2048 + pos] = t * 2 + 1;
}

__global__ void offs_kernel(const int* __restrict__ cnt, int* __restrict__ offs)
{
    if (threadIdx.x == 0) {
        int s = 0;
        for (int e = 0; e < 8; e++) { offs[e] = s; s += cnt[e]; }
    }
}

// ---------------- MoE GEMM1: hid = GELU(tn2h @ f16(w1[e])^T + b1) -----------
// 256x128 tile, 512 thr / 8 waves. T2 XOR-swizzled LDS (key (row>>1)&3):
// A via pre-swizzled gload16 source; B ds_write at swizzled slot; reads at
// col ((l>>4)^((l>>1)&3))*8. XCD = expert: bid = e + 8*(n_i + 32*m_i).
__global__ __launch_bounds__(512) void moe_gemm1_kernel(
    const _Float16* __restrict__ tn2h, const float* __restrict__ w1f,
    const float* __restrict__ b1, const int* __restrict__ cnt, const int* __restrict__ offs,
    const int* __restrict__ entry, _Float16* __restrict__ hid)
{
    int bid = blockIdx.x;
    int e = bid & 7;
    int n_i = (bid >> 3) & 31;
    int m_i = bid >> 8;                   // 0..7
    int ne = cnt[e];
    int m0 = m_i * 256;
    if (m0 >= ne) return;
    int n0 = n_i * 128;
    __shared__ _Float16 As[2][256 * 32];
    __shared__ _Float16 Bs[2][128 * 32];
    int t = threadIdx.x, w = t >> 6, l = t & 63;
    int sa = l >> 2;
    int swz = (l >> 3) & 3;                       // key(row) = (row>>1)&3, row = l>>2
    int scA = ((l & 3) ^ swz) * 8;                // pre-swizzled A source col
    int scB = (l & 3) * 8;                        // B source col (floats)
    int rcol = (((l >> 4) ^ ((l >> 1) & 3)) * 8); // swizzled read col
    int g0 = entry[e * 2048 + min(m0 + w * 32 + sa, ne - 1)] >> 1;
    int g1 = entry[e * 2048 + min(m0 + w * 32 + 16 + sa, ne - 1)] >> 1;
    const _Float16* gA0 = tn2h + (size_t)g0 * DMODEL + scA;
    const _Float16* gA1 = tn2h + (size_t)g1 * DMODEL + scA;
    const float* w1e = w1f + (size_t)e * HEXP * DMODEL;
    const float* gB0f = w1e + (size_t)(n0 + w * 16 + sa) * DMODEL + scB;
    const int aoff0 = (w * 32) * 32, aoff1 = (w * 32 + 16) * 32;
    const int boff0 = (w * 16 + sa) * 32 + ((l & 3) ^ swz) * 8;
    int wr = w >> 1, wc = w & 1;
    f32x4 zero = { 0.0f, 0.0f, 0.0f, 0.0f };
    f32x4 acc[4][4];
#pragma unroll
    for (int i = 0; i < 4; i++)
#pragma unroll
        for (int j = 0; j < 4; j++) acc[i][j] = zero;
    f32x4 br0, br1;

#define M1_LOADB(K0) do { \
    br0 = *(const f32x4*)(gB0f + (K0)); \
    br1 = *(const f32x4*)(gB0f + (K0) + 4); \
} while (0)

#define M1_STAGE(B, K0) do { \
    half8 hb0 = { (_Float16)br0[0], (_Float16)br0[1], (_Float16)br0[2], (_Float16)br0[3], \
                  (_Float16)br1[0], (_Float16)br1[1], (_Float16)br1[2], (_Float16)br1[3] }; \
    *(half8*)&Bs[B][boff0] = hb0; \
    gload16(gA0 + (K0), &As[B][aoff0]); gload16(gA1 + (K0), &As[B][aoff1]); \
    WAIT_LGKM0; \
} while (0)

#define M1_COMPUTE(B) do { \
    half8 af[4], bfr[4]; \
    _Pragma("unroll") \
    for (int mi = 0; mi < 4; mi++) \
        af[mi] = *(const half8*)&As[B][(wr * 64 + mi * 16 + (l & 15)) * 32 + rcol]; \
    _Pragma("unroll") \
    for (int ni = 0; ni < 4; ni++) \
        bfr[ni] = *(const half8*)&Bs[B][(wc * 64 + ni * 16 + (l & 15)) * 32 + rcol]; \
    _Pragma("unroll") \
    for (int mi = 0; mi < 4; mi++) \
        _Pragma("unroll") \
        for (int ni = 0; ni < 4; ni++) \
            acc[mi][ni] = __builtin_amdgcn_mfma_f32_16x16x32_f16(af[mi], bfr[ni], acc[mi][ni], 0, 0, 0); \
} while (0)

    const int nt = DMODEL >> 5;            // 32, even
    M1_LOADB(0);
    M1_STAGE(0, 0);
    M1_LOADB(32);
    for (int kt = 0; kt < nt; kt += 2) {
        M1_STAGE(1, (kt + 1) << 5);
        if (kt + 2 < nt) M1_LOADB((kt + 2) << 5);
        WAIT_VM4;
        BARRIER; SCHEDFENCE;
        M1_COMPUTE(0);
        BARRIER;
        if (kt + 2 < nt) {
            M1_STAGE(0, (kt + 2) << 5);
            if (kt + 3 < nt) M1_LOADB((kt + 3) << 5);
            WAIT_VM4;
        } else {
            WAIT_VM0;
        }
        BARRIER; SCHEDFENCE;
        M1_COMPUTE(1);
        BARRIER;
    }
#undef M1_LOADB
#undef M1_STAGE
#undef M1_COMPUTE

    int off_e = offs[e];
#pragma unroll
    for (int mi = 0; mi < 4; mi++) {
#pragma unroll
        for (int r = 0; r < 4; r++) {
            int row = m0 + wr * 64 + mi * 16 + (l >> 4) * 4 + r;
            if (row < ne) {
                size_t orow = (size_t)(off_e + row) * HEXP;
#pragma unroll
                for (int ni = 0; ni < 4; ni++) {
                    int cg = n0 + wc * 64 + ni * 16 + (l & 15);
                    float v = acc[mi][ni][r] + b1[e * HEXP + cg];
                    hid[orow + cg] = (_Float16)gelu_fast(v);
                }
            }
        }
    }
}

// ---------------- MoE GEMM2: eo = hid @ f16(w2[e])^T (+b2) ------------------
// 256x128 tile, 512 thr / 8 waves, K-split x4. Same T2 XOR-swizzled LDS as
// gemm1. Partials stored f16 (halves eo HBM traffic).
// XCD = expert: bid = e + 8*(n_i + 8*(ks + 4*m_i)).
__global__ __launch_bounds__(512) void moe_gemm2_kernel(
    const _Float16* __restrict__ hid, const float* __restrict__ w2f,
    const float* __restrict__ b2, const int* __restrict__ cnt, const int* __restrict__ offs,
    const int* __restrict__ entry,
    _Float16* __restrict__ eoA, _Float16* __restrict__ eoB,
    _Float16* __restrict__ eoC, _Float16* __restrict__ eoD)
{
    int bid = blockIdx.x;
    int e = bid & 7;                      // XCD = expert (balanced: ne ~ equal)
    int rest = bid >> 3;
    int n_i = rest & 7;
    int rest2 = rest >> 3;
    int ks = rest2 & 3;
    int m_i = rest2 >> 2;
    int ne = cnt[e];
    int m0 = m_i * 256;
    if (m0 >= ne) return;
    int n0 = n_i * 128;
    int kbase = ks * (HEXP / 4);
    _Float16* eoP = (ks == 0) ? eoA : (ks == 1) ? eoB : (ks == 2) ? eoC : eoD;
    __shared__ _Float16 As[2][256 * 32];
    __shared__ _Float16 Bs[2][128 * 32];
    int t = threadIdx.x, w = t >> 6, l = t & 63;
    int off_e = offs[e];
    int sa = l >> 2;
    int swz = (l >> 3) & 3;
    int scA = ((l & 3) ^ swz) * 8;
    int scB = (l & 3) * 8;
    int rcol = (((l >> 4) ^ ((l >> 1) & 3)) * 8);
    int r0 = off_e + min(m0 + w * 32 + sa, ne - 1);
    int r1 = off_e + min(m0 + w * 32 + 16 + sa, ne - 1);
    const _Float16* gA0 = hid + (size_t)r0 * HEXP + kbase + scA;
    const _Float16* gA1 = hid + (size_t)r1 * HEXP + kbase + scA;
    const float* w2e = w2f + (size_t)e * DMODEL * HEXP;
    const float* gB0f = w2e + (size_t)(n0 + w * 16 + sa) * HEXP + kbase + scB;
    const int aoff0 = (w * 32) * 32, aoff1 = (w * 32 + 16) * 32;
    const int boff0 = (w * 16 + sa) * 32 + ((l & 3) ^ swz) * 8;
    int wr = w >> 1, wc = w & 1;
    f32x4 zero = { 0.0f, 0.0f, 0.0f, 0.0f };
    f32x4 acc[4][4];
#pragma unroll
    for (int i = 0; i < 4; i++)
#pragma unroll
        for (int j = 0; j < 4; j++) acc[i][j] = zero;
    f32x4 br0, br1;

#define M2_LOADB(K0) do { \
    br0 = *(const f32x4*)(gB0f + (K0)); \
    br1 = *(const f32x4*)(gB0f + (K0) + 4); \
} while (0)

#define M2_STAGE(B, K0) do { \
    half8 hb0 = { (_Float16)br0[0], (_Float16)br0[1], (_Float16)br0[2], (_Float16)br0[3], \
                  (_Float16)br1[0], (_Float16)br1[1], (_Float16)br1[2], (_Float16)br1[3] }; \
    *(half8*)&Bs[B][boff0] = hb0; \
    gload16(gA0 + (K0), &As[B][aoff0]); gload16(gA1 + (K0), &As[B][aoff1]); \
    WAIT_LGKM0; \
} while (0)

#define M2_COMPUTE(B) do { \
    half8 af[4], bfr[4]; \
    _Pragma("unroll") \
    for (int mi = 0; mi < 4; mi++) \
        af[mi] = *(const half8*)&As[B][(wr * 64 + mi * 16 + (l & 15)) * 32 + rcol]; \
    _Pragma("unroll") \
    for (int ni = 0; ni < 4; ni++) \
        bfr[ni] = *(const half8*)&Bs[B][(wc * 64 + ni * 16 + (l & 15)) * 32 + rcol]; \
    _Pragma("unroll") \
    for (int mi = 0; mi < 4; mi++) \
        _Pragma("unroll") \
        for (int ni = 0; ni < 4; ni++) \
            acc[mi][ni] = __builtin_amdgcn_mfma_f32_16x16x32_f16(af[mi], bfr[ni], acc[mi][ni], 0, 0, 0); \
} while (0)

    const int nt = (HEXP / 4) >> 5;        // 32, even
    M2_LOADB(0);
    M2_STAGE(0, 0);
    M2_LOADB(32);
    for (int kt = 0; kt < nt; kt += 2) {
        M2_STAGE(1, (kt + 1) << 5);
        if (kt + 2 < nt) M2_LOADB((kt + 2) << 5);
        WAIT_VM4;
        BARRIER; SCHEDFENCE;
        M2_COMPUTE(0);
        BARRIER;
        if (kt + 2 < nt) {
            M2_STAGE(0, (kt + 2) << 5);
            if (kt + 3 < nt) M2_LOADB((kt + 3) << 5);
            WAIT_VM4;
        } else {
            WAIT_VM0;
        }
        BARRIER; SCHEDFENCE;
        M2_COMPUTE(1);
        BARRIER;
    }
#undef M2_LOADB
#undef M2_STAGE
#undef M2_COMPUTE

#pragma unroll
    for (int mi = 0; mi < 4; mi++) {
#pragma unroll
        for (int r = 0; r < 4; r++) {
            int row = m0 + wr * 64 + mi * 16 + (l >> 4) * 4 + r;
            if (row < ne) {
                int t2k = entry[e * 2048 + row];
#pragma unroll
                for (int ni = 0; ni < 4; ni++) {
                    int cg = n0 + wc * 64 + ni * 16 + (l & 15);
                    float v = acc[mi][ni][r];
                    if (ks == 0) v += b2[e * DMODEL + cg];
                    eoP[(size_t)t2k * DMODEL + cg] = (_Float16)v;
                }
            }
        }
    }
}

// ---------------- final: out = h + sum_k rw_k * (eoA+eoB+eoC+eoD) -----------
__global__ __launch_bounds__(256) void combine_kernel(const float* __restrict__ hf,
                                                      const _Float16* __restrict__ eoA,
                                                      const _Float16* __restrict__ eoB,
                                                      const _Float16* __restrict__ eoC,
                                                      const _Float16* __restrict__ eoD,
                                                      const float* __restrict__ rw,
                                                      float* __restrict__ out)
{
    int i = blockIdx.x * 256 + threadIdx.x;   // 4-elem group index over 524288
    int tok = i >> 8;
    int d4 = i & 255;
    float4 hv = ((const float4*)hf)[i];
    float p0 = rw[tok * 2], p1 = rw[tok * 2 + 1];
    size_t i0 = ((size_t)(tok * 2) * 256 + d4) * 4;
    size_t i1 = ((size_t)(tok * 2 + 1) * 256 + d4) * 4;
    half4 a0 = *(const half4*)(eoA + i0);
    half4 b0 = *(const half4*)(eoB + i0);
    half4 c0 = *(const half4*)(eoC + i0);
    half4 d0 = *(const half4*)(eoD + i0);
    half4 a1 = *(const half4*)(eoA + i1);
    half4 b1 = *(const half4*)(eoB + i1);
    half4 c1 = *(const half4*)(eoC + i1);
    half4 d1 = *(const half4*)(eoD + i1);
    float4 o;
    o.x = hv.x + p0 * ((float)a0[0] + (float)b0[0] + (float)c0[0] + (float)d0[0])
               + p1 * ((float)a1[0] + (float)b1[0] + (float)c1[0] + (float)d1[0]);
    o.y = hv.y + p0 * ((float)a0[1] + (float)b0[1] + (float)c0[1] + (float)d0[1])
               + p1 * ((float)a1[1] + (float)b1[1] + (float)c1[1] + (float)d1[1]);
    o.z = hv.z + p0 * ((float)a0[2] + (float)b0[2] + (float)c0[2] + (float)d0[2])
               + p1 * ((float)a1[2] + (float)b1[2] + (float)c1[2] + (float)d1[2]);
    o.w = hv.w + p0 * ((float)a0[3] + (float)b0[3] + (float)c0[3] + (float)d0[3])
               + p1 * ((float)a1[3] + (float)b1[3] + (float)c1[3] + (float)d1[3]);
    ((float4*)out)[i] = o;
}

// ---------------------------------------------------------------------------
extern "C" void kernel_launch(void* const* d_in, const int* in_sizes, int n_in,
                              void* d_out, int out_size, void* d_ws, size_t ws_size,
                              hipStream_t stream)
{
    const float* x   = (const float*)d_in[0];
    const float* anw = (const float*)d_in[1];
    const float* wq  = (const float*)d_in[2];
    const float* wk  = (const float*)d_in[3];
    const float* wv  = (const float*)d_in[4];
    const float* wo  = (const float*)d_in[5];
    const float* mnw = (const float*)d_in[6];
    const float* gw  = (const float*)d_in[7];
    const float* w1  = (const float*)d_in[8];
    const float* b1  = (const float*)d_in[9];
    const float* w2  = (const float*)d_in[10];
    const float* b2  = (const float*)d_in[11];
    float* out = (float*)d_out;

    char* p = (char*)d_ws;
    auto alloc = [&](size_t bytes) { char* q = p; p += (bytes + 255) & ~(size_t)255; return q; };
    const size_t TD = (size_t)T_TOK * DMODEL;
    unsigned short* tnHi = (unsigned short*)alloc(TD * 2);
    unsigned short* tnLo = (unsigned short*)alloc(TD * 2);
    float*    qf   = (float*)alloc(TD * 4);
    float*    kf   = (float*)alloc(TD * 4);
    float*    vf   = (float*)alloc(TD * 4);
    unsigned short* qHi = (unsigned short*)alloc(TD * 2);
    unsigned short* qLo = (unsigned short*)alloc(TD * 2);
    unsigned short* kHi = (unsigned short*)alloc(TD * 2);
    unsigned short* kLo = (unsigned short*)alloc(TD * 2);
    float*    hf   = (float*)alloc(TD * 4);
    unsigned short* wqH = (unsigned short*)alloc((size_t)DMODEL * DMODEL * 2);
    unsigned short* wqL = (unsigned short*)alloc((size_t)DMODEL * DMODEL * 2);
    unsigned short* wkH = (unsigned short*)alloc((size_t)DMODEL * DMODEL * 2);
    unsigned short* wkL = (unsigned short*)alloc((size_t)DMODEL * DMODEL * 2);
    unsigned short* wvH = (unsigned short*)alloc((size_t)DMODEL * DMODEL * 2);
    unsigned short* wvL = (unsigned short*)alloc((size_t)DMODEL * DMODEL * 2);
    unsigned short* woH = (unsigned short*)alloc((size_t)DMODEL * DMODEL * 2);
    unsigned short* woL = (unsigned short*)alloc((size_t)DMODEL * DMODEL * 2);
    char*     moescr = alloc((size_t)64 * 1024 * 1024);   // Opart / eoC / eoD
    _Float16* hid  = (_Float16*)alloc((size_t)4096 * HEXP * 2);
    float*    logits = (float*)alloc((size_t)T_TOK * NEXP * 4);
    float*    rw   = (float*)alloc((size_t)T_TOK * 2 * 4);
    int*      cnt  = (int*)alloc(256);
    int*      offs = (int*)alloc(256);
    int*      entry = (int*)alloc((size_t)NEXP * 2048 * 4);
    float*    mscr = (float*)alloc((size_t)2 * 32 * SEQ * 4);
    float*    lscr = (float*)alloc((size_t)2 * 32 * SEQ * 4);
    (void)ws_size; (void)in_sizes; (void)n_in; (void)out_size;

    // aliases (lifetimes): qf dead after rope -> vtHi/vtLo (dead after attn) -> tn2f
    unsigned short* vtHi = (unsigned short*)qf;
    unsigned short* vtLo = (unsigned short*)qf + TD;
    float* tn2f = qf;
    // kf dead after rope -> aoHi/aoLo
    unsigned short* aoHi = (unsigned short*)kf;
    unsigned short* aoLo = (unsigned short*)kf + TD;
    // vf dead after vtrans -> tn2h
    _Float16* tn2h = (_Float16*)vf;
    // qHi..kLo (16MB contiguous, dead after attn) -> eoA (f16, 8.4MB fits)
    _Float16* eoA = (_Float16*)qHi;
    // wqH..woL (16MB contiguous, dead after O-proj) -> eoB (f16)
    _Float16* eoB = (_Float16*)wqH;
    // moescr (64MB): [0,16.8MB) attn Opart (dead after attn_combine);
    // [32MB,..) eoC, [48MB,..) eoD (f16) — written by gemm2, read by combine.
    float* Opart = (float*)moescr;
    _Float16* eoC = (_Float16*)(moescr + (size_t)32 * 1024 * 1024);
    _Float16* eoD = (_Float16*)(moescr + (size_t)48 * 1024 * 1024);

    // attention weight splits (one fused launch)
    split4_kernel<<<dim3(512, 4), 256, 0, stream>>>(wq, wk, wv, wo,
        wqH, wkH, wvH, woH, wqL, wkL, wvL, woL, DMODEL * DMODEL / 4);

    // attention path (split-bf16 MFMA end-to-end)
    rmsnorm_kernel<<<T_TOK, 256, 0, stream>>>(x, anw, nullptr, (_Float16*)nullptr, tnHi, tnLo);
    gemm_split_kernel<<<dim3(16, 16, 3), 256, 0, stream>>>(
        tnHi, tnLo, wqH, wqL, wkH, wkL, wvH, wvL, qf, kf, vf, nullptr, DMODEL);
    rope_split_kernel<<<4096, 256, 0, stream>>>(qf, kf, qHi, qLo, kHi, kLo);
    vtrans_kernel<<<dim3(16, 32), 256, 0, stream>>>(vf, vtHi, vtLo);
    attn_mfma_kernel<<<dim3(8, 32, 2), 512, 0, stream>>>(qHi, qLo, kHi, kLo, vtHi, vtLo,
                                                         Opart, mscr, lscr);
    attn_combine_kernel<<<2048, 256, 0, stream>>>(Opart, mscr, lscr, aoHi, aoLo);
    gemm_split_kernel<<<dim3(16, 16, 1), 256, 0, stream>>>(
        aoHi, aoLo, woH, woL, woH, woL, woH, woL, hf, hf, hf, x, DMODEL);

    // MoE (no weight casts: gemm1/gemm2 read f32 weights directly)
    rmsnorm_kernel<<<T_TOK, 256, 0, stream>>>(hf, mnw, tn2f, tn2h, nullptr, nullptr);
    gate_kernel<<<T_TOK, 256, 0, stream>>>(tn2f, gw, logits);
    zero_kernel<<<1, 64, 0, stream>>>(cnt, 8);
    top2_kernel<<<8, 256, 0, stream>>>(logits, rw, cnt, entry);
    offs_kernel<<<1, 1, 0, stream>>>(cnt, offs);
    moe_gemm1_kernel<<<2048, 512, 0, stream>>>(tn2h, w1, b1, cnt, offs, entry, hid);
    moe_gemm2_kernel<<<2048, 512, 0, stream>>>(hid, w2, b2, cnt, offs, entry,
                                               eoA, eoB, eoC, eoD);
    combine_kernel<<<2048, 256, 0, stream>>>(hf, eoA, eoB, eoC, eoD, rw, out);
}